// Round 9
// baseline (1903.585 us; speedup 1.0000x reference)
//
#include <hip/hip_runtime.h>
#include <hip/hip_bf16.h>

typedef __hip_bfloat16 bf16;
typedef unsigned short u16;
typedef unsigned int u32;
typedef __attribute__((ext_vector_type(8))) short short8;
typedef __attribute__((ext_vector_type(4))) float f32x4;
typedef __attribute__((ext_vector_type(4))) unsigned int u32x4;

#define NPART 30000
#define NEDGE 300000
#define HD 128
#define NLAYER 10
#define NFLOAT_ARRAYS 43
#define NMAT 66

// ---------------- dtype detect ----------------
__device__ __forceinline__ bool detect_bf16(const unsigned short* braw) {
    return braw[1] == 0x3F80u;
}

// ---------------- fp32<->bf16 helpers (HW cvt_pk via compiler) ----------------
__device__ __forceinline__ u16 f2b(float f) {
    const bf16 h = __float2bfloat16(f);
    u16 u;
    __builtin_memcpy(&u, &h, sizeof(u));
    return u;
}
__device__ __forceinline__ u32 pack2(float a, float b) {
    return (u32)f2b(a) | ((u32)f2b(b) << 16);
}
__device__ __forceinline__ float b2flo(u32 u) { return __uint_as_float(u << 16); }
__device__ __forceinline__ float b2fhi(u32 u) { return __uint_as_float(u & 0xFFFF0000u); }

// ---------------- non-temporal 16B accessors ----------------
__device__ __forceinline__ u32x4 ntl4(const u16* p) {
    return __builtin_nontemporal_load((const u32x4*)p);
}
__device__ __forceinline__ void nts4(const u32x4 v, u16* p) {
    __builtin_nontemporal_store(v, (u32x4*)p);
}
__device__ __forceinline__ f32x4 ntlf4(const float* p) {
    return __builtin_nontemporal_load((const f32x4*)p);
}
__device__ __forceinline__ void ntsf4(const f32x4 v, float* p) {
    __builtin_nontemporal_store(v, (f32x4*)p);
}

// ---------------- convert all float arrays to canonical fp32 ----------------
struct ConvArgs {
    const void* src[NFLOAT_ARRAYS];
    int n[NFLOAT_ARRAYS];
    int off[NFLOAT_ARRAYS];
};

__global__ __launch_bounds__(256)
void k_convert(ConvArgs a, float* __restrict__ dst, const unsigned short* __restrict__ braw)
{
    const bool isb = detect_bf16(braw);
    const int aid = blockIdx.y;
    const int n = a.n[aid];
    float* o = dst + a.off[aid];
    const int stride = gridDim.x * 256;
    int i = blockIdx.x * 256 + threadIdx.x;
    if (isb) {
        const unsigned short* s = (const unsigned short*)a.src[aid];
        for (; i < n; i += stride) {
            const unsigned int u = ((unsigned int)s[i]) << 16;
            o[i] = __uint_as_float(u);
        }
    } else {
        const float* s = (const float*)a.src[aid];
        for (; i < n; i += stride) o[i] = s[i];
    }
}

// ---------------- counting sort of edges by receiver ----------------
__global__ __launch_bounds__(256)
void k_hist(const int* __restrict__ rcv, int* __restrict__ counts)
{
    const int e = blockIdx.x * 256 + threadIdx.x;
    if (e < NEDGE) atomicAdd(&counts[rcv[e]], 1);
}

__global__ __launch_bounds__(1024)
void k_scan(const int* __restrict__ counts, int* __restrict__ row_ptr, int* __restrict__ cursor)
{
    __shared__ int part[1024];
    const int t = threadIdx.x;
    const int base = t * 32;
    int local[32];
    int s = 0;
#pragma unroll
    for (int k = 0; k < 32; k++) {
        const int idx = base + k;
        const int v = (idx < NPART) ? counts[idx] : 0;
        local[k] = s;
        s += v;
    }
    part[t] = s;
    __syncthreads();
    for (int off = 1; off < 1024; off <<= 1) {
        const int v = (t >= off) ? part[t - off] : 0;
        __syncthreads();
        part[t] += v;
        __syncthreads();
    }
    const int excl = (t == 0) ? 0 : part[t - 1];
#pragma unroll
    for (int k = 0; k < 32; k++) {
        const int idx = base + k;
        if (idx < NPART) {
            const int rp = excl + local[k];
            row_ptr[idx] = rp;
            cursor[idx] = rp;
        }
    }
    if (t == 0) row_ptr[NPART] = NEDGE;
}

__global__ __launch_bounds__(256)
void k_scatter(const int* __restrict__ snd, const int* __restrict__ rcv,
               int* __restrict__ cursor, int* __restrict__ snd_s, int* __restrict__ rcv_s)
{
    const int e = blockIdx.x * 256 + threadIdx.x;
    if (e < NEDGE) {
        const int r = rcv[e];
        const int p = atomicAdd(&cursor[r], 1);
        snd_s[p] = snd[e];
        rcv_s[p] = r;
    }
}

// ---------------- weight pre-pack: f32 [K][128] -> bf16 fragment-linear ----------------
struct PackArgs {
    int src_off[NMAT];
    int dst_off[NMAT];
    int K[NMAT];
    int nks[NMAT];
};

__global__ __launch_bounds__(256)
void k_pack(const float* __restrict__ cw, u16* __restrict__ wpk, PackArgs pa)
{
    const int mid = blockIdx.y;
    const int nks = pa.nks[mid];
    const int total = nks * 4096;
    const int d = blockIdx.x * 256 + threadIdx.x;
    if (d >= total) return;
    const int j = d & 7, l = (d >> 3) & 63, t = d >> 9;
    const int ks = t % nks, mt = t / nks;
    const int hid = mt * 16 + (l & 15);
    const int k = ks * 32 + (l >> 4) * 8 + j;
    const float v = (k < pa.K[mid]) ? cw[pa.src_off[mid] + k * HD + hid] : 0.0f;
    wpk[pa.dst_off[mid] + d] = f2b(v);
}

// ================= 4-wave (256-thr) 64-row MFMA MLP: encoders =================
template<int NKS, int XROW>
__device__ __forceinline__ void gemm16(const u16* __restrict__ Wp,
                                       const float* __restrict__ Bias,
                                       const u16* __restrict__ x,
                                       f32x4 acc[4][2],
                                       const int wm, const int wn,
                                       const int l15, const int lg, const int lane)
{
#pragma unroll
    for (int mt = 0; mt < 4; mt++) {
        const f32x4 bv = *(const f32x4*)(Bias + wm * 64 + mt * 16 + lg * 4);
        acc[mt][0] = bv;
        acc[mt][1] = bv;
    }
    const u16* xr0 = x + (wn * 32 + l15) * XROW + lg * 8;
    const u16* xr1 = xr0 + 16 * XROW;
    const u16* wp = Wp + (wm * 4 * NKS) * 512 + lane * 8;
#pragma unroll
    for (int ks = 0; ks < NKS; ks++) {
        const short8 b0 = *(const short8*)(xr0 + ks * 32);
        const short8 b1 = *(const short8*)(xr1 + ks * 32);
#pragma unroll
        for (int mt = 0; mt < 4; mt++) {
            const short8 a = *(const short8*)(wp + (mt * NKS + ks) * 512);
            acc[mt][0] = __builtin_amdgcn_mfma_f32_16x16x32_bf16(a, b0, acc[mt][0], 0, 0, 0);
            acc[mt][1] = __builtin_amdgcn_mfma_f32_16x16x32_bf16(a, b1, acc[mt][1], 0, 0, 0);
        }
    }
}

__device__ __forceinline__ void store_h(u16* __restrict__ h, const f32x4 acc[4][2],
                                        const int wm, const int wn, const int l15, const int lg)
{
#pragma unroll
    for (int nt = 0; nt < 2; nt++) {
        const int e = wn * 32 + nt * 16 + l15;
#pragma unroll
        for (int mt = 0; mt < 4; mt++) {
            const int hid = wm * 64 + mt * 16 + lg * 4;
            const f32x4 v = acc[mt][nt];
            const u32 lo = pack2(fmaxf(v[0], 0.0f), fmaxf(v[1], 0.0f));
            const u32 hi = pack2(fmaxf(v[2], 0.0f), fmaxf(v[3], 0.0f));
            *(uint2*)(h + e * 136 + hid) = make_uint2(lo, hi);
        }
    }
}

template<int NKS1, int XROW>
__device__ __forceinline__ void mlp_mfma(const u16* __restrict__ xs,
    u16* __restrict__ h1, u16* __restrict__ h2,
    float (*red)[2][2][16][2],
    const u16* __restrict__ W1p, const float* __restrict__ B1,
    const u16* __restrict__ W2p, const float* __restrict__ B2,
    const u16* __restrict__ W3p, const float* __restrict__ B3,
    const float* __restrict__ g, const float* __restrict__ be,
    float outv[4][2][4],
    const int wm, const int wn, const int l15, const int lg, const int lane)
{
    f32x4 acc[4][2];
    gemm16<NKS1, XROW>(W1p, B1, xs, acc, wm, wn, l15, lg, lane);
    __syncthreads();
    store_h(h1, acc, wm, wn, l15, lg);
    __syncthreads();
    gemm16<4, 136>(W2p, B2, h1, acc, wm, wn, l15, lg, lane);
    store_h(h2, acc, wm, wn, l15, lg);
    __syncthreads();
    gemm16<4, 136>(W3p, B3, h2, acc, wm, wn, l15, lg, lane);
    float ps[2], pss[2];
#pragma unroll
    for (int nt = 0; nt < 2; nt++) {
        float s = 0.0f, ss = 0.0f;
#pragma unroll
        for (int mt = 0; mt < 4; mt++) {
#pragma unroll
            for (int r = 0; r < 4; r++) {
                const float v = acc[mt][nt][r];
                s += v; ss += v * v;
            }
        }
        s += __shfl_xor(s, 16); ss += __shfl_xor(ss, 16);
        s += __shfl_xor(s, 32); ss += __shfl_xor(ss, 32);
        ps[nt] = s; pss[nt] = ss;
    }
    if (lane < 16) {
#pragma unroll
        for (int nt = 0; nt < 2; nt++) {
            red[wm][wn][nt][l15][0] = ps[nt];
            red[wm][wn][nt][l15][1] = pss[nt];
        }
    }
    __syncthreads();
#pragma unroll
    for (int nt = 0; nt < 2; nt++) {
        const float S  = red[0][wn][nt][l15][0] + red[1][wn][nt][l15][0];
        const float SS = red[0][wn][nt][l15][1] + red[1][wn][nt][l15][1];
        const float mu  = S * (1.0f / 128.0f);
        const float var = SS * (1.0f / 128.0f) - mu * mu;
        const float inv = rsqrtf(var + 1e-5f);
#pragma unroll
        for (int mt = 0; mt < 4; mt++) {
            const int hid = wm * 64 + mt * 16 + lg * 4;
            const f32x4 gv  = *(const f32x4*)(g + hid);
            const f32x4 bev = *(const f32x4*)(be + hid);
#pragma unroll
            for (int r = 0; r < 4; r++)
                outv[mt][nt][r] = (acc[mt][nt][r] - mu) * inv * gv[r] + bev[r];
        }
    }
}

// ---------------- node encoder (K=30 padded to 32), bf16 node state ----------------
__device__ __forceinline__ float nfeat(int i, int k,
    const float* __restrict__ vel, const float* __restrict__ pos,
    const float* __restrict__ bounds, const int* __restrict__ ptype,
    const float* __restrict__ emb)
{
    if (k < 10) return vel[i * 10 + k];
    if (k < 14) {
        const int q = k - 10;
        float sub;
        if (q < 2) sub = pos[i * 2 + q] - bounds[q * 2 + 0];
        else       sub = bounds[(q - 2) * 2 + 1] - pos[i * 2 + (q - 2)];
        const float dv = sub * 20.0f;
        return fminf(fmaxf(dv, -1.0f), 1.0f);
    }
    if (k < 30) return emb[ptype[i] * 16 + (k - 14)];
    return 0.0f;
}

__global__ __launch_bounds__(256)
void k_node_enc_m(const float* __restrict__ vel, const float* __restrict__ pos,
                  const float* __restrict__ bounds, const int* __restrict__ ptype,
                  const float* __restrict__ emb,
                  const u16* __restrict__ W1p, const float* __restrict__ B1,
                  const u16* __restrict__ W2p, const float* __restrict__ B2,
                  const u16* __restrict__ W3p, const float* __restrict__ B3,
                  const float* __restrict__ g, const float* __restrict__ be,
                  u16* __restrict__ nodes_bf)
{
    __shared__ __align__(16) u16 lds[17408];
    __shared__ float red[2][2][2][16][2];
    const int tid = threadIdx.x;
    const int i0 = blockIdx.x * 64;
    for (int idx = tid; idx < 1024; idx += 256) {
        const int m = idx >> 4, kk = idx & 15;
        const int i = i0 + m;
        float f0 = 0.0f, f1 = 0.0f;
        if (i < NPART) {
            f0 = nfeat(i, kk * 2 + 0, vel, pos, bounds, ptype, emb);
            f1 = nfeat(i, kk * 2 + 1, vel, pos, bounds, ptype, emb);
        }
        *(u32*)(lds + m * 40 + kk * 2) = pack2(f0, f1);
    }
    __syncthreads();
    const int lane = tid & 63, wv = tid >> 6;
    const int wm = wv >> 1, wn = wv & 1, l15 = lane & 15, lg = lane >> 4;
    float outv[4][2][4];
    mlp_mfma<1, 40>(lds, lds, lds + 8704, red, W1p, B1, W2p, B2, W3p, B3, g, be,
                    outv, wm, wn, l15, lg, lane);
#pragma unroll
    for (int nt = 0; nt < 2; nt++) {
        const int i = i0 + wn * 32 + nt * 16 + l15;
        if (i < NPART) {
#pragma unroll
            for (int mt = 0; mt < 4; mt++) {
                const int hid = wm * 64 + mt * 16 + lg * 4;
                *(uint2*)(nodes_bf + (size_t)i * HD + hid) =
                    make_uint2(pack2(outv[mt][nt][0], outv[mt][nt][1]),
                               pack2(outv[mt][nt][2], outv[mt][nt][3]));
            }
        }
    }
}

// ------------- edge encoder (K=3 padded to 32), sorted order, bf16 output -------------
__global__ __launch_bounds__(256)
void k_edge_enc_m(const float* __restrict__ pos, const int* __restrict__ snd_s,
                  const int* __restrict__ rcv_s,
                  const u16* __restrict__ W1p, const float* __restrict__ B1,
                  const u16* __restrict__ W2p, const float* __restrict__ B2,
                  const u16* __restrict__ W3p, const float* __restrict__ B3,
                  const float* __restrict__ g, const float* __restrict__ be,
                  u16* __restrict__ edges_bf)
{
    __shared__ __align__(16) u16 lds[17408];
    __shared__ float red[2][2][2][16][2];
    const int tid = threadIdx.x;
    const int e0 = blockIdx.x * 64;
    for (int idx = tid; idx < 1024; idx += 256) {
        const int m = idx >> 4, kk = idx & 15;
        const int e = min(e0 + m, NEDGE - 1);
        u32 w = 0;
        if (kk < 2) {
            const int s = snd_s[e], r = rcv_s[e];
            const float dx = (pos[s * 2 + 0] - pos[r * 2 + 0]) * 20.0f;
            const float dy = (pos[s * 2 + 1] - pos[r * 2 + 1]) * 20.0f;
            if (kk == 0) w = pack2(dx, dy);
            else         w = pack2(sqrtf(dx * dx + dy * dy), 0.0f);
        }
        *(u32*)(lds + m * 40 + kk * 2) = w;
    }
    __syncthreads();
    const int lane = tid & 63, wv = tid >> 6;
    const int wm = wv >> 1, wn = wv & 1, l15 = lane & 15, lg = lane >> 4;
    float outv[4][2][4];
    mlp_mfma<1, 40>(lds, lds, lds + 8704, red, W1p, B1, W2p, B2, W3p, B3, g, be,
                    outv, wm, wn, l15, lg, lane);
#pragma unroll
    for (int nt = 0; nt < 2; nt++) {
        const int e = e0 + wn * 32 + nt * 16 + l15;
        if (e < NEDGE) {
#pragma unroll
            for (int mt = 0; mt < 4; mt++) {
                const int hid = wm * 64 + mt * 16 + lg * 4;
                *(uint2*)(edges_bf + (size_t)e * HD + hid) =
                    make_uint2(pack2(outv[mt][nt][0], outv[mt][nt][1]),
                               pack2(outv[mt][nt][2], outv[mt][nt][3]));
            }
        }
    }
}

// ======= 4-wave (256-thr) 32-row pipelined edge layer, bf16 state, NT streams =======
__device__ __forceinline__ void egemm_seg32(const u16* __restrict__ Wp,
                                            const u16* __restrict__ x,
                                            f32x4 acc[2][2], const int ks0,
                                            const int wm,
                                            const int l15, const int lg, const int lane)
{
    const u16* xr0 = x + l15 * 136 + lg * 8;
    const u16* xr1 = xr0 + 16 * 136;
#pragma unroll
    for (int ks = 0; ks < 4; ks++) {
        const short8 b0 = *(const short8*)(xr0 + ks * 32);
        const short8 b1 = *(const short8*)(xr1 + ks * 32);
#pragma unroll
        for (int mt = 0; mt < 2; mt++) {
            const short8 a = *(const short8*)(Wp + (((wm * 2 + mt) * 12 + ks0 + ks) * 64 + lane) * 8);
            acc[mt][0] = __builtin_amdgcn_mfma_f32_16x16x32_bf16(a, b0, acc[mt][0], 0, 0, 0);
            acc[mt][1] = __builtin_amdgcn_mfma_f32_16x16x32_bf16(a, b1, acc[mt][1], 0, 0, 0);
        }
    }
}

__device__ __forceinline__ void egemm_h32(const u16* __restrict__ Wp,
                                          const float* __restrict__ Bias,
                                          const u16* __restrict__ x,
                                          f32x4 acc[2][2],
                                          const int wm,
                                          const int l15, const int lg, const int lane)
{
#pragma unroll
    for (int mt = 0; mt < 2; mt++) {
        const f32x4 bv = *(const f32x4*)(Bias + wm * 32 + mt * 16 + lg * 4);
        acc[mt][0] = bv;
        acc[mt][1] = bv;
    }
    const u16* xr0 = x + l15 * 136 + lg * 8;
    const u16* xr1 = xr0 + 16 * 136;
#pragma unroll
    for (int ks = 0; ks < 4; ks++) {
        const short8 b0 = *(const short8*)(xr0 + ks * 32);
        const short8 b1 = *(const short8*)(xr1 + ks * 32);
#pragma unroll
        for (int mt = 0; mt < 2; mt++) {
            const short8 a = *(const short8*)(Wp + (((wm * 2 + mt) * 4 + ks) * 64 + lane) * 8);
            acc[mt][0] = __builtin_amdgcn_mfma_f32_16x16x32_bf16(a, b0, acc[mt][0], 0, 0, 0);
            acc[mt][1] = __builtin_amdgcn_mfma_f32_16x16x32_bf16(a, b1, acc[mt][1], 0, 0, 0);
        }
    }
}

// K=256 node GEMM1: 8 K-steps, xs stride 264, weight nks=8
__device__ __forceinline__ void egemm_n1(const u16* __restrict__ Wp,
                                         const float* __restrict__ Bias,
                                         const u16* __restrict__ x,
                                         f32x4 acc[2][2],
                                         const int wm,
                                         const int l15, const int lg, const int lane)
{
#pragma unroll
    for (int mt = 0; mt < 2; mt++) {
        const f32x4 bv = *(const f32x4*)(Bias + wm * 32 + mt * 16 + lg * 4);
        acc[mt][0] = bv;
        acc[mt][1] = bv;
    }
    const u16* xr0 = x + l15 * 264 + lg * 8;
    const u16* xr1 = xr0 + 16 * 264;
#pragma unroll
    for (int ks = 0; ks < 8; ks++) {
        const short8 b0 = *(const short8*)(xr0 + ks * 32);
        const short8 b1 = *(const short8*)(xr1 + ks * 32);
#pragma unroll
        for (int mt = 0; mt < 2; mt++) {
            const short8 a = *(const short8*)(Wp + (((wm * 2 + mt) * 8 + ks) * 64 + lane) * 8);
            acc[mt][0] = __builtin_amdgcn_mfma_f32_16x16x32_bf16(a, b0, acc[mt][0], 0, 0, 0);
            acc[mt][1] = __builtin_amdgcn_mfma_f32_16x16x32_bf16(a, b1, acc[mt][1], 0, 0, 0);
        }
    }
}

__device__ __forceinline__ void estore_h32(u16* __restrict__ h, const f32x4 acc[2][2],
                                           const int wm, const int l15, const int lg)
{
#pragma unroll
    for (int nt = 0; nt < 2; nt++) {
        const int row = nt * 16 + l15;
#pragma unroll
        for (int mt = 0; mt < 2; mt++) {
            const int hid = wm * 32 + mt * 16 + lg * 4;
            const f32x4 v = acc[mt][nt];
            const u32 lo = pack2(fmaxf(v[0], 0.0f), fmaxf(v[1], 0.0f));
            const u32 hi = pack2(fmaxf(v[2], 0.0f), fmaxf(v[3], 0.0f));
            *(uint2*)(h + row * 136 + hid) = make_uint2(lo, hi);
        }
    }
}

__global__ __launch_bounds__(256, 8)
void k_edge_layer_m(const u16* __restrict__ nodes_bf, u16* __restrict__ edges_bf,
                    float* __restrict__ agg, float* __restrict__ bnd,
                    const int* __restrict__ snd_s, const int* __restrict__ rcv_s,
                    const u16* __restrict__ W1p, const float* __restrict__ B1,
                    const u16* __restrict__ W2p, const float* __restrict__ B2,
                    const u16* __restrict__ W3p, const float* __restrict__ B3,
                    const float* __restrict__ g, const float* __restrict__ be)
{
    __shared__ __align__(16) u16 sb[2 * 4352];   // b0,b1: 32x136 bf16; fout overlays
    __shared__ float red[4][2][16][2];
    __shared__ int rblk[34];                     // [0..31] receivers, 32=prev, 33=next
    u16* b0 = sb;
    u16* b1 = sb + 4352;
    float* fout = (float*)sb;                    // 32 rows x stride 132 f32 = 16896B

    const int tid = threadIdx.x;
    // XCD-bijective tile swizzle (m204): consecutive tiles colocate per XCD
    const int nwg = NEDGE / 32;                  // 9375
    const int qq = nwg >> 3, rr = nwg & 7;       // 1171, 7
    const int xcd = blockIdx.x & 7, sub = blockIdx.x >> 3;
    const int tile = (xcd < rr ? xcd * (qq + 1) : rr * (qq + 1) + (xcd - rr) * qq) + sub;
    const int e0 = tile * 32;
    const int lane = tid & 63, wm = tid >> 6;
    const int l15 = lane & 15, lg = lane >> 4;

    if (tid < 32)       rblk[tid] = rcv_s[e0 + tid];
    else if (tid == 32) rblk[32] = (e0 > 0) ? rcv_s[e0 - 1] : -2;
    else if (tid == 33) rblk[33] = (e0 + 32 < NEDGE) ? rcv_s[e0 + 32] : -2;

    // stage seg0 (edge rows, bf16, non-temporal) into b0; keep old in regs
    u32x4 e_old[2];
#pragma unroll
    for (int t = 0; t < 2; t++) {
        const int idx = tid + t * 256;
        const int m = idx >> 4, q = idx & 15;
        e_old[t] = ntl4(edges_bf + (size_t)(e0 + m) * HD + q * 8);
        *(u32x4*)(b0 + m * 136 + q * 8) = e_old[t];
    }
    // issue seg1 (sender rows, bf16, cached) loads -> regs
    u32x4 st[2];
#pragma unroll
    for (int t = 0; t < 2; t++) {
        const int idx = tid + t * 256;
        const int m = idx >> 4, q = idx & 15;
        st[t] = *(const u32x4*)(nodes_bf + (size_t)snd_s[e0 + m] * HD + q * 8);
    }
    __syncthreads();

    f32x4 acc[2][2];
#pragma unroll
    for (int mt = 0; mt < 2; mt++) {
        const f32x4 bv = *(const f32x4*)(B1 + wm * 32 + mt * 16 + lg * 4);
        acc[mt][0] = bv;
        acc[mt][1] = bv;
    }
    __builtin_amdgcn_s_setprio(1);
    egemm_seg32(W1p, b0, acc, 0, wm, l15, lg, lane);
    __builtin_amdgcn_s_setprio(0);
    // write seg1 -> b1, issue seg2 (receiver rows) loads
#pragma unroll
    for (int t = 0; t < 2; t++) {
        const int idx = tid + t * 256;
        const int m = idx >> 4, q = idx & 15;
        *(u32x4*)(b1 + m * 136 + q * 8) = st[t];
    }
#pragma unroll
    for (int t = 0; t < 2; t++) {
        const int idx = tid + t * 256;
        const int m = idx >> 4, q = idx & 15;
        st[t] = *(const u32x4*)(nodes_bf + (size_t)rcv_s[e0 + m] * HD + q * 8);
    }
    __syncthreads();

    __builtin_amdgcn_s_setprio(1);
    egemm_seg32(W1p, b1, acc, 4, wm, l15, lg, lane);
    __builtin_amdgcn_s_setprio(0);
#pragma unroll
    for (int t = 0; t < 2; t++) {
        const int idx = tid + t * 256;
        const int m = idx >> 4, q = idx & 15;
        *(u32x4*)(b0 + m * 136 + q * 8) = st[t];
    }
    __syncthreads();

    __builtin_amdgcn_s_setprio(1);
    egemm_seg32(W1p, b0, acc, 8, wm, l15, lg, lane);
    __builtin_amdgcn_s_setprio(0);
    estore_h32(b1, acc, wm, l15, lg);      // b1 free: all waves past prev barrier
    __syncthreads();

    __builtin_amdgcn_s_setprio(1);
    egemm_h32(W2p, B2, b1, acc, wm, l15, lg, lane);
    __builtin_amdgcn_s_setprio(0);
    estore_h32(b0, acc, wm, l15, lg);      // b0 free
    __syncthreads();

    __builtin_amdgcn_s_setprio(1);
    egemm_h32(W3p, B3, b0, acc, wm, l15, lg, lane);
    __builtin_amdgcn_s_setprio(0);

    // ---- layernorm reduction ----
    float ps[2], pss[2];
#pragma unroll
    for (int nt = 0; nt < 2; nt++) {
        float s = 0.0f, ss = 0.0f;
#pragma unroll
        for (int mt = 0; mt < 2; mt++) {
#pragma unroll
            for (int r = 0; r < 4; r++) {
                const float v = acc[mt][nt][r];
                s += v; ss += v * v;
            }
        }
        s += __shfl_xor(s, 16); ss += __shfl_xor(ss, 16);
        s += __shfl_xor(s, 32); ss += __shfl_xor(ss, 32);
        ps[nt] = s; pss[nt] = ss;
    }
    if (lane < 16) {
#pragma unroll
        for (int nt = 0; nt < 2; nt++) {
            red[wm][nt][l15][0] = ps[nt];
            red[wm][nt][l15][1] = pss[nt];
        }
    }
    __syncthreads();   // red ready; all waves past GEMM3 -> b0/b1 dead, fout may overlay

    // ---- LN apply -> fout (f32, stride 132) ----
#pragma unroll
    for (int nt = 0; nt < 2; nt++) {
        const float S  = red[0][nt][l15][0] + red[1][nt][l15][0]
                       + red[2][nt][l15][0] + red[3][nt][l15][0];
        const float SS = red[0][nt][l15][1] + red[1][nt][l15][1]
                       + red[2][nt][l15][1] + red[3][nt][l15][1];
        const float mu  = S * (1.0f / 128.0f);
        const float var = SS * (1.0f / 128.0f) - mu * mu;
        const float inv = rsqrtf(var + 1e-5f);
        const int row = nt * 16 + l15;
#pragma unroll
        for (int mt = 0; mt < 2; mt++) {
            const int hid = wm * 32 + mt * 16 + lg * 4;
            const f32x4 gv  = *(const f32x4*)(g + hid);
            const f32x4 bev = *(const f32x4*)(be + hid);
            f32x4 o;
#pragma unroll
            for (int r = 0; r < 4; r++)
                o[r] = (acc[mt][nt][r] - mu) * inv * gv[r] + bev[r];
            *(f32x4*)(fout + row * 132 + hid) = o;
        }
    }
    __syncthreads();

    // ---- writer: new = b2f(old regs) + ln; NT bf16 row write; new(f32) -> fout ----
#pragma unroll
    for (int t = 0; t < 2; t++) {
        const int idx = tid + t * 256;
        const int m = idx >> 4, q = idx & 15;
        float4 lo = *(const float4*)(fout + m * 132 + q * 8);
        float4 hi = *(const float4*)(fout + m * 132 + q * 8 + 4);
        const u32x4 o = e_old[t];
        lo.x += b2flo(o.x); lo.y += b2fhi(o.x);
        lo.z += b2flo(o.y); lo.w += b2fhi(o.y);
        hi.x += b2flo(o.z); hi.y += b2fhi(o.z);
        hi.z += b2flo(o.w); hi.w += b2fhi(o.w);
        *(float4*)(fout + m * 132 + q * 8) = lo;
        *(float4*)(fout + m * 132 + q * 8 + 4) = hi;
        u32x4 nv;
        nv.x = pack2(lo.x, lo.y); nv.y = pack2(lo.z, lo.w);
        nv.z = pack2(hi.x, hi.y); nv.w = pack2(hi.z, hi.w);
        nts4(nv, edges_bf + (size_t)(e0 + m) * HD + q * 8);
    }
    __syncthreads();

    // ---- aggregation: run sums -> agg (interior) or bnd (boundary), NT stores ----
    const int c = tid & 31;              // float4 chunk 0..31
    for (int ms = (tid >> 5); ms < 32; ms += 8) {
        const int rs = rblk[ms];
        if (ms > 0 && rblk[ms - 1] == rs) continue;   // not a run start
        int me = ms + 1;
        while (me < 32 && rblk[me] == rs) me++;
        f32x4 s = {0.0f, 0.0f, 0.0f, 0.0f};
        for (int m = ms; m < me; m++) {
            const float4 v = *(const float4*)(fout + m * 132 + c * 4);
            s.x += v.x; s.y += v.y; s.z += v.z; s.w += v.w;
        }
        const bool extb = (ms == 0 && rblk[32] == rs);
        const bool extf = (me == 32 && rblk[33] == rs);
        float* ap;
        if (!extb && !extf) ap = agg + (size_t)rs * HD + c * 4;
        else ap = bnd + ((size_t)tile * 2 + (extb ? 0 : 1)) * HD + c * 4;
        ntsf4(s, ap);
    }
}

// ======= 4-wave (256-thr) 32-row node layer; bf16 state, agg/bnd reassembly =======
__global__ __launch_bounds__(256)
void k_node_layer_m(u16* __restrict__ nodes_bf,
                    const float* __restrict__ agg, const float* __restrict__ bnd,
                    const int* __restrict__ row_ptr,
                    const u16* __restrict__ W1p, const float* __restrict__ B1,
                    const u16* __restrict__ W2p, const float* __restrict__ B2,
                    const u16* __restrict__ W3p, const float* __restrict__ B3,
                    const float* __restrict__ g, const float* __restrict__ be)
{
    __shared__ __align__(16) u16 xs[32 * 264];   // 16896 B; h2 overlays (stride 136)
    __shared__ __align__(16) u16 hb[32 * 136];   // 8704 B
    __shared__ float red[4][2][16][2];
    __shared__ int rp[33];
    const int tid = threadIdx.x;
    const int i0 = blockIdx.x * 32;
    const int lane = tid & 63, wm = tid >> 6;
    const int l15 = lane & 15, lg = lane >> 4;
    if (tid < 33) rp[tid] = row_ptr[min(i0 + tid, NPART)];
    __syncthreads();
    // seg A: bf16 node rows, straight copy
#pragma unroll
    for (int t = 0; t < 2; t++) {
        const int idx = tid + t * 256;
        const int m = idx >> 4, q = idx & 15;
        const int i = min(i0 + m, NPART - 1);
        *(u32x4*)(xs + m * 264 + q * 8) =
            *(const u32x4*)(nodes_bf + (size_t)i * HD + q * 8);
    }
    // seg B: agg/bnd reassembly (NT loads)
#pragma unroll
    for (int t = 0; t < 2; t++) {
        const int idx = tid + t * 256;
        const int m = idx >> 4, q = idx & 15;
        const int i = i0 + m;
        f32x4 a = {0.0f, 0.0f, 0.0f, 0.0f};
        f32x4 b = {0.0f, 0.0f, 0.0f, 0.0f};
        if (i < NPART) {
            const int p0 = rp[m], p1 = rp[m + 1];
            if (p1 > p0) {
                const int b0i = p0 >> 5, b1i = (p1 - 1) >> 5;
                if (b0i == b1i) {
                    const float* src = agg + (size_t)i * HD + q * 8;
                    a = ntlf4(src);
                    b = ntlf4(src + 4);
                } else {
                    const float* s1 = bnd + ((size_t)b0i * 2 + 1) * HD + q * 8;
                    a = ntlf4(s1);
                    b = ntlf4(s1 + 4);
                    for (int bb = b0i + 1; bb <= b1i; bb++) {
                        const float* s0 = bnd + ((size_t)bb * 2 + 0) * HD + q * 8;
                        a += ntlf4(s0);
                        b += ntlf4(s0 + 4);
                    }
                }
            }
        }
        *(u32x4*)(xs + m * 264 + 128 + q * 8) = (u32x4){
            pack2(a.x, a.y), pack2(a.z, a.w), pack2(b.x, b.y), pack2(b.z, b.w)};
    }
    __syncthreads();

    f32x4 acc[2][2];
    __builtin_amdgcn_s_setprio(1);
    egemm_n1(W1p, B1, xs, acc, wm, l15, lg, lane);
    __builtin_amdgcn_s_setprio(0);
    estore_h32(hb, acc, wm, l15, lg);       // hb disjoint from xs
    __syncthreads();
    __builtin_amdgcn_s_setprio(1);
    egemm_h32(W2p, B2, hb, acc, wm, l15, lg, lane);
    __builtin_amdgcn_s_setprio(0);
    estore_h32(xs, acc, wm, l15, lg);       // xs dead (all waves past gemm1 barrier)
    __syncthreads();
    __builtin_amdgcn_s_setprio(1);
    egemm_h32(W3p, B3, xs, acc, wm, l15, lg, lane);
    __builtin_amdgcn_s_setprio(0);

    // ---- layernorm ----
    float ps[2], pss[2];
#pragma unroll
    for (int nt = 0; nt < 2; nt++) {
        float s = 0.0f, ss = 0.0f;
#pragma unroll
        for (int mt = 0; mt < 2; mt++) {
#pragma unroll
            for (int r = 0; r < 4; r++) {
                const float v = acc[mt][nt][r];
                s += v; ss += v * v;
            }
        }
        s += __shfl_xor(s, 16); ss += __shfl_xor(ss, 16);
        s += __shfl_xor(s, 32); ss += __shfl_xor(ss, 32);
        ps[nt] = s; pss[nt] = ss;
    }
    if (lane < 16) {
#pragma unroll
        for (int nt = 0; nt < 2; nt++) {
            red[wm][nt][l15][0] = ps[nt];
            red[wm][nt][l15][1] = pss[nt];
        }
    }
    __syncthreads();

    // ---- LN apply + residual (bf16 re-read, L2-hot) + write ----
#pragma unroll
    for (int nt = 0; nt < 2; nt++) {
        const float S  = red[0][nt][l15][0] + red[1][nt][l15][0]
                       + red[2][nt][l15][0] + red[3][nt][l15][0];
        const float SS = red[0][nt][l15][1] + red[1][nt][l15][1]
                       + red[2][nt][l15][1] + red[3][nt][l15][1];
        const float mu  = S * (1.0f / 128.0f);
        const float var = SS * (1.0f / 128.0f) - mu * mu;
        const float inv = rsqrtf(var + 1e-5f);
        const int i = i0 + nt * 16 + l15;
        if (i < NPART) {
            u16* np = nodes_bf + (size_t)i * HD;
#pragma unroll
            for (int mt = 0; mt < 2; mt++) {
                const int hid = wm * 32 + mt * 16 + lg * 4;
                const f32x4 gv  = *(const f32x4*)(g + hid);
                const f32x4 bev = *(const f32x4*)(be + hid);
                const uint2 ob = *(const uint2*)(np + hid);
                float4 nv;
                nv.x = b2flo(ob.x) + (acc[mt][nt][0] - mu) * inv * gv[0] + bev[0];
                nv.y = b2fhi(ob.x) + (acc[mt][nt][1] - mu) * inv * gv[1] + bev[1];
                nv.z = b2flo(ob.y) + (acc[mt][nt][2] - mu) * inv * gv[2] + bev[2];
                nv.w = b2fhi(ob.y) + (acc[mt][nt][3] - mu) * inv * gv[3] + bev[3];
                *(uint2*)(np + hid) = make_uint2(pack2(nv.x, nv.y), pack2(nv.z, nv.w));
            }
        }
    }
}

// ---------------- fp32 gemv for decoder ----------------
template<int K, int S>
__device__ __forceinline__ void gemv(const float* __restrict__ in,
                                     const float* __restrict__ W,
                                     const float* __restrict__ B,
                                     float acc[8])
{
    const int j = threadIdx.x;
    const float bb = B[j];
#pragma unroll
    for (int m = 0; m < 8; m++) acc[m] = bb;
    constexpr int K4 = (K / 4) * 4;
    for (int k = 0; k < K4; k += 4) {
        const float w0 = W[(k + 0) * HD + j];
        const float w1 = W[(k + 1) * HD + j];
        const float w2 = W[(k + 2) * HD + j];
        const float w3 = W[(k + 3) * HD + j];
#pragma unroll
        for (int m = 0; m < 8; m++) {
            const float4 x = *(const float4*)(in + m * S + k);
            float a = acc[m];
            a = fmaf(x.x, w0, a);
            a = fmaf(x.y, w1, a);
            a = fmaf(x.z, w2, a);
            a = fmaf(x.w, w3, a);
            acc[m] = a;
        }
    }
#pragma unroll
    for (int k = K4; k < K; k++) {
        const float w = W[k * HD + j];
#pragma unroll
        for (int m = 0; m < 8; m++) acc[m] = fmaf(in[m * S + k], w, acc[m]);
    }
}

// ---------------- decoder + Euler integration (dual output dtype) ----------------
__global__ __launch_bounds__(128)
void k_decoder(const u16* __restrict__ nodes_bf,
               const float* W1, const float* B1, const float* W2, const float* B2,
               const float* W3, const float* B3,
               const float* __restrict__ vel, const float* __restrict__ pos,
               const float* __restrict__ tgt, const int* __restrict__ nonk,
               const unsigned short* __restrict__ braw, void* __restrict__ d_out)
{
    __shared__ __align__(16) float xs[8 * HD];
    __shared__ __align__(16) float h1[8 * HD];
    __shared__ __align__(16) float h2[8 * HD];
    const int j = threadIdx.x;
    const int i0 = blockIdx.x * 8;
    float acc[8];
    for (int idx = j; idx < 512; idx += 128) {
        const int m = idx >> 6, q = idx & 63;
        const u32 w = *(const u32*)(nodes_bf + (size_t)(i0 + m) * HD + q * 2);
        xs[m * HD + q * 2]     = b2flo(w);
        xs[m * HD + q * 2 + 1] = b2fhi(w);
    }
    __syncthreads();
    gemv<HD, HD>(xs, W1, B1, acc);
#pragma unroll
    for (int m = 0; m < 8; m++) h1[m * HD + j] = fmaxf(acc[m], 0.0f);
    __syncthreads();
    gemv<HD, HD>(h1, W2, B2, acc);
#pragma unroll
    for (int m = 0; m < 8; m++) h2[m * HD + j] = fmaxf(acc[m], 0.0f);
    __syncthreads();
    if (j < 16) {
        const int m = j >> 1, d = j & 1, i = i0 + m;
        float a = B3[d];
        for (int k = 0; k < HD; k++) a = fmaf(h2[m * HD + k], W3[k * 2 + d], a);
        float pp = pos[i * 2 + d] + vel[i * 10 + 8 + d] + a;
        if (nonk[i] == 0) pp = tgt[i * 2 + d];
        if (detect_bf16(braw)) {
            bf16* o = (bf16*)d_out;
            o[i * 2 + d] = __float2bfloat16(a);
            o[2 * NPART + i * 2 + d] = __float2bfloat16(pp);
        } else {
            float* o = (float*)d_out;
            o[i * 2 + d] = a;
            o[2 * NPART + i * 2 + d] = pp;
        }
    }
}

extern "C" void kernel_launch(void* const* d_in, const int* in_sizes, int n_in,
                              void* d_out, int out_size, void* d_ws, size_t ws_size,
                              hipStream_t stream)
{
    const int* ptype = (const int*)d_in[4];
    const int* nonk  = (const int*)d_in[5];
    const int* snd   = (const int*)d_in[6];
    const int* rcv   = (const int*)d_in[7];
    const unsigned short* braw = (const unsigned short*)d_in[2];

    int fmap[NFLOAT_ARRAYS];
    {
        int c = 0;
        fmap[c++] = 0; fmap[c++] = 1; fmap[c++] = 2; fmap[c++] = 3; fmap[c++] = 8;
        for (int i = 9; i <= 46; i++) fmap[c++] = i;
    }
    ConvArgs ca;
    const float* fp[47];
    float* cw = (float*)d_ws;
    int off = 0;
    for (int i = 0; i < NFLOAT_ARRAYS; i++) {
        ca.src[i] = d_in[fmap[i]];
        ca.n[i]   = in_sizes[fmap[i]];
        ca.off[i] = off;
        fp[fmap[i]] = cw + off;
        off += in_sizes[fmap[i]];
    }
    const int EB32 = NEDGE / 32;        // 9375 (edge layer, exact)
    // workspace: agg + bnd + bf16 edge state + bf16 node state + weights + sort scratch
    float* agg   = cw + ((off + 3) & ~3);
    float* bnd   = agg + (size_t)NPART * HD;
    u16* edges_bf = (u16*)(bnd + (size_t)EB32 * 2 * HD);
    u16* nodes_bf = edges_bf + (size_t)NEDGE * HD;
    u16* wpk = nodes_bf + (size_t)NPART * HD;

    // build pack table (order: ne x3, ee x3, ge x30, gn x30)
    PackArgs pa;
    int dst = 0, c = 0;
    int pk[NMAT];
    auto addm = [&](long srcoff, int K) {
        const int nk = (K + 31) / 32;
        pa.src_off[c] = (int)srcoff;
        pa.K[c] = K;
        pa.nks[c] = nk;
        pa.dst_off[c] = dst;
        pk[c] = dst;
        dst += nk * 4096;
        c++;
    };
    addm(fp[9]  - cw, 30);  addm(fp[11] - cw, 128); addm(fp[13] - cw, 128);
    addm(fp[17] - cw, 3);   addm(fp[19] - cw, 128); addm(fp[21] - cw, 128);
    for (int l = 0; l < NLAYER; l++) {
        addm(fp[25] - cw + (long)l * 384 * HD, 384);
        addm(fp[27] - cw + (long)l * HD * HD, 128);
        addm(fp[29] - cw + (long)l * HD * HD, 128);
    }
    for (int l = 0; l < NLAYER; l++) {
        addm(fp[33] - cw + (long)l * 256 * HD, 256);
        addm(fp[35] - cw + (long)l * HD * HD, 128);
        addm(fp[37] - cw + (long)l * HD * HD, 128);
    }

    int* ip = (int*)(wpk + ((dst + 7) & ~7));
    int* row_ptr = ip;            ip += NPART + 8;
    int* cursor  = ip;            ip += NPART;
    int* counts  = ip;            ip += NPART;
    int* snd_s   = ip;            ip += NEDGE;
    int* rcv_s   = ip;

    const int EBL = (NEDGE + 255) / 256;

    k_convert<<<dim3(64, NFLOAT_ARRAYS), 256, 0, stream>>>(ca, cw, braw);
    hipMemsetAsync(counts, 0, (size_t)NPART * sizeof(int), stream);
    k_hist<<<EBL, 256, 0, stream>>>(rcv, counts);
    k_scan<<<1, 1024, 0, stream>>>(counts, row_ptr, cursor);
    k_scatter<<<EBL, 256, 0, stream>>>(snd, rcv, cursor, snd_s, rcv_s);
    k_pack<<<dim3(192, NMAT), 256, 0, stream>>>(cw, wpk, pa);

    const int NB = (NPART + 63) / 64;     // 469 (encoder)
    const int NB32 = (NPART + 31) / 32;   // 938 (node layer)
    const int EB = (NEDGE + 63) / 64;     // 4688 (edge encoder)

    k_node_enc_m<<<NB, 256, 0, stream>>>(fp[0], fp[1], fp[2], ptype, fp[8],
        wpk + pk[0], fp[10], wpk + pk[1], fp[12], wpk + pk[2], fp[14],
        fp[15], fp[16], nodes_bf);
    k_edge_enc_m<<<EB, 256, 0, stream>>>(fp[1], snd_s, rcv_s,
        wpk + pk[3], fp[18], wpk + pk[4], fp[20], wpk + pk[5], fp[22],
        fp[23], fp[24], edges_bf);

    for (int l = 0; l < NLAYER; l++) {
        k_edge_layer_m<<<EB32, 256, 0, stream>>>(nodes_bf, edges_bf, agg, bnd, snd_s, rcv_s,
            wpk + pk[6 + 3 * l],  fp[26] + (size_t)l * HD,
            wpk + pk[7 + 3 * l],  fp[28] + (size_t)l * HD,
            wpk + pk[8 + 3 * l],  fp[30] + (size_t)l * HD,
            fp[31] + (size_t)l * HD, fp[32] + (size_t)l * HD);
        k_node_layer_m<<<NB32, 256, 0, stream>>>(nodes_bf, agg, bnd, row_ptr,
            wpk + pk[36 + 3 * l], fp[34] + (size_t)l * HD,
            wpk + pk[37 + 3 * l], fp[36] + (size_t)l * HD,
            wpk + pk[38 + 3 * l], fp[38] + (size_t)l * HD,
            fp[39] + (size_t)l * HD, fp[40] + (size_t)l * HD);
    }

    k_decoder<<<NPART / 8, 128, 0, stream>>>(nodes_bf,
        fp[41], fp[42], fp[43], fp[44], fp[45], fp[46],
        fp[0], fp[1], fp[3], nonk, braw, d_out);
}

// Round 10
// 1892.922 us; speedup vs baseline: 1.0056x; 1.0056x over previous
//
#include <hip/hip_runtime.h>
#include <hip/hip_bf16.h>

typedef __hip_bfloat16 bf16;
typedef unsigned short u16;
typedef unsigned int u32;
typedef __attribute__((ext_vector_type(8))) short short8;
typedef __attribute__((ext_vector_type(4))) float f32x4;
typedef __attribute__((ext_vector_type(4))) unsigned int u32x4;

#define NPART 30000
#define NEDGE 300000
#define HD 128
#define NLAYER 10
#define NFLOAT_ARRAYS 43
#define NMAT 66

// ---------------- dtype detect ----------------
__device__ __forceinline__ bool detect_bf16(const unsigned short* braw) {
    return braw[1] == 0x3F80u;
}

// ---------------- fp32<->bf16 helpers (HW cvt_pk via compiler) ----------------
__device__ __forceinline__ u16 f2b(float f) {
    const bf16 h = __float2bfloat16(f);
    u16 u;
    __builtin_memcpy(&u, &h, sizeof(u));
    return u;
}
__device__ __forceinline__ u32 pack2(float a, float b) {
    return (u32)f2b(a) | ((u32)f2b(b) << 16);
}
__device__ __forceinline__ float b2flo(u32 u) { return __uint_as_float(u << 16); }
__device__ __forceinline__ float b2fhi(u32 u) { return __uint_as_float(u & 0xFFFF0000u); }

// ---------------- non-temporal 16B accessors ----------------
__device__ __forceinline__ u32x4 ntl4(const u16* p) {
    return __builtin_nontemporal_load((const u32x4*)p);
}
__device__ __forceinline__ void nts4(const u32x4 v, u16* p) {
    __builtin_nontemporal_store(v, (u32x4*)p);
}
__device__ __forceinline__ f32x4 ntlf4(const float* p) {
    return __builtin_nontemporal_load((const f32x4*)p);
}
__device__ __forceinline__ void ntsf4(const f32x4 v, float* p) {
    __builtin_nontemporal_store(v, (f32x4*)p);
}

// ---------------- convert all float arrays to canonical fp32 ----------------
struct ConvArgs {
    const void* src[NFLOAT_ARRAYS];
    int n[NFLOAT_ARRAYS];
    int off[NFLOAT_ARRAYS];
};

__global__ __launch_bounds__(256)
void k_convert(ConvArgs a, float* __restrict__ dst, const unsigned short* __restrict__ braw)
{
    const bool isb = detect_bf16(braw);
    const int aid = blockIdx.y;
    const int n = a.n[aid];
    float* o = dst + a.off[aid];
    const int stride = gridDim.x * 256;
    int i = blockIdx.x * 256 + threadIdx.x;
    if (isb) {
        const unsigned short* s = (const unsigned short*)a.src[aid];
        for (; i < n; i += stride) {
            const unsigned int u = ((unsigned int)s[i]) << 16;
            o[i] = __uint_as_float(u);
        }
    } else {
        const float* s = (const float*)a.src[aid];
        for (; i < n; i += stride) o[i] = s[i];
    }
}

// ---------------- counting sort of edges by receiver ----------------
__global__ __launch_bounds__(256)
void k_hist(const int* __restrict__ rcv, int* __restrict__ counts)
{
    const int e = blockIdx.x * 256 + threadIdx.x;
    if (e < NEDGE) atomicAdd(&counts[rcv[e]], 1);
}

__global__ __launch_bounds__(1024)
void k_scan(const int* __restrict__ counts, int* __restrict__ row_ptr, int* __restrict__ cursor)
{
    __shared__ int part[1024];
    const int t = threadIdx.x;
    const int base = t * 32;
    int local[32];
    int s = 0;
#pragma unroll
    for (int k = 0; k < 32; k++) {
        const int idx = base + k;
        const int v = (idx < NPART) ? counts[idx] : 0;
        local[k] = s;
        s += v;
    }
    part[t] = s;
    __syncthreads();
    for (int off = 1; off < 1024; off <<= 1) {
        const int v = (t >= off) ? part[t - off] : 0;
        __syncthreads();
        part[t] += v;
        __syncthreads();
    }
    const int excl = (t == 0) ? 0 : part[t - 1];
#pragma unroll
    for (int k = 0; k < 32; k++) {
        const int idx = base + k;
        if (idx < NPART) {
            const int rp = excl + local[k];
            row_ptr[idx] = rp;
            cursor[idx] = rp;
        }
    }
    if (t == 0) row_ptr[NPART] = NEDGE;
}

__global__ __launch_bounds__(256)
void k_scatter(const int* __restrict__ snd, const int* __restrict__ rcv,
               int* __restrict__ cursor, int* __restrict__ snd_s, int* __restrict__ rcv_s)
{
    const int e = blockIdx.x * 256 + threadIdx.x;
    if (e < NEDGE) {
        const int r = rcv[e];
        const int p = atomicAdd(&cursor[r], 1);
        snd_s[p] = snd[e];
        rcv_s[p] = r;
    }
}

// ---------------- weight pre-pack: f32 [K][128] -> bf16 fragment-linear ----------------
struct PackArgs {
    int src_off[NMAT];
    int dst_off[NMAT];
    int K[NMAT];
    int nks[NMAT];
};

__global__ __launch_bounds__(256)
void k_pack(const float* __restrict__ cw, u16* __restrict__ wpk, PackArgs pa)
{
    const int mid = blockIdx.y;
    const int nks = pa.nks[mid];
    const int total = nks * 4096;
    const int d = blockIdx.x * 256 + threadIdx.x;
    if (d >= total) return;
    const int j = d & 7, l = (d >> 3) & 63, t = d >> 9;
    const int ks = t % nks, mt = t / nks;
    const int hid = mt * 16 + (l & 15);
    const int k = ks * 32 + (l >> 4) * 8 + j;
    const float v = (k < pa.K[mid]) ? cw[pa.src_off[mid] + k * HD + hid] : 0.0f;
    wpk[pa.dst_off[mid] + d] = f2b(v);
}

// ================= 4-wave (256-thr) 64-row MFMA MLP: encoders =================
template<int NKS, int XROW>
__device__ __forceinline__ void gemm16(const u16* __restrict__ Wp,
                                       const float* __restrict__ Bias,
                                       const u16* __restrict__ x,
                                       f32x4 acc[4][2],
                                       const int wm, const int wn,
                                       const int l15, const int lg, const int lane)
{
#pragma unroll
    for (int mt = 0; mt < 4; mt++) {
        const f32x4 bv = *(const f32x4*)(Bias + wm * 64 + mt * 16 + lg * 4);
        acc[mt][0] = bv;
        acc[mt][1] = bv;
    }
    const u16* xr0 = x + (wn * 32 + l15) * XROW + lg * 8;
    const u16* xr1 = xr0 + 16 * XROW;
    const u16* wp = Wp + (wm * 4 * NKS) * 512 + lane * 8;
#pragma unroll
    for (int ks = 0; ks < NKS; ks++) {
        const short8 b0 = *(const short8*)(xr0 + ks * 32);
        const short8 b1 = *(const short8*)(xr1 + ks * 32);
#pragma unroll
        for (int mt = 0; mt < 4; mt++) {
            const short8 a = *(const short8*)(wp + (mt * NKS + ks) * 512);
            acc[mt][0] = __builtin_amdgcn_mfma_f32_16x16x32_bf16(a, b0, acc[mt][0], 0, 0, 0);
            acc[mt][1] = __builtin_amdgcn_mfma_f32_16x16x32_bf16(a, b1, acc[mt][1], 0, 0, 0);
        }
    }
}

__device__ __forceinline__ void store_h(u16* __restrict__ h, const f32x4 acc[4][2],
                                        const int wm, const int wn, const int l15, const int lg)
{
#pragma unroll
    for (int nt = 0; nt < 2; nt++) {
        const int e = wn * 32 + nt * 16 + l15;
#pragma unroll
        for (int mt = 0; mt < 4; mt++) {
            const int hid = wm * 64 + mt * 16 + lg * 4;
            const f32x4 v = acc[mt][nt];
            const u32 lo = pack2(fmaxf(v[0], 0.0f), fmaxf(v[1], 0.0f));
            const u32 hi = pack2(fmaxf(v[2], 0.0f), fmaxf(v[3], 0.0f));
            *(uint2*)(h + e * 136 + hid) = make_uint2(lo, hi);
        }
    }
}

template<int NKS1, int XROW>
__device__ __forceinline__ void mlp_mfma(const u16* __restrict__ xs,
    u16* __restrict__ h1, u16* __restrict__ h2,
    float (*red)[2][2][16][2],
    const u16* __restrict__ W1p, const float* __restrict__ B1,
    const u16* __restrict__ W2p, const float* __restrict__ B2,
    const u16* __restrict__ W3p, const float* __restrict__ B3,
    const float* __restrict__ g, const float* __restrict__ be,
    float outv[4][2][4],
    const int wm, const int wn, const int l15, const int lg, const int lane)
{
    f32x4 acc[4][2];
    gemm16<NKS1, XROW>(W1p, B1, xs, acc, wm, wn, l15, lg, lane);
    __syncthreads();
    store_h(h1, acc, wm, wn, l15, lg);
    __syncthreads();
    gemm16<4, 136>(W2p, B2, h1, acc, wm, wn, l15, lg, lane);
    store_h(h2, acc, wm, wn, l15, lg);
    __syncthreads();
    gemm16<4, 136>(W3p, B3, h2, acc, wm, wn, l15, lg, lane);
    float ps[2], pss[2];
#pragma unroll
    for (int nt = 0; nt < 2; nt++) {
        float s = 0.0f, ss = 0.0f;
#pragma unroll
        for (int mt = 0; mt < 4; mt++) {
#pragma unroll
            for (int r = 0; r < 4; r++) {
                const float v = acc[mt][nt][r];
                s += v; ss += v * v;
            }
        }
        s += __shfl_xor(s, 16); ss += __shfl_xor(ss, 16);
        s += __shfl_xor(s, 32); ss += __shfl_xor(ss, 32);
        ps[nt] = s; pss[nt] = ss;
    }
    if (lane < 16) {
#pragma unroll
        for (int nt = 0; nt < 2; nt++) {
            red[wm][wn][nt][l15][0] = ps[nt];
            red[wm][wn][nt][l15][1] = pss[nt];
        }
    }
    __syncthreads();
#pragma unroll
    for (int nt = 0; nt < 2; nt++) {
        const float S  = red[0][wn][nt][l15][0] + red[1][wn][nt][l15][0];
        const float SS = red[0][wn][nt][l15][1] + red[1][wn][nt][l15][1];
        const float mu  = S * (1.0f / 128.0f);
        const float var = SS * (1.0f / 128.0f) - mu * mu;
        const float inv = rsqrtf(var + 1e-5f);
#pragma unroll
        for (int mt = 0; mt < 4; mt++) {
            const int hid = wm * 64 + mt * 16 + lg * 4;
            const f32x4 gv  = *(const f32x4*)(g + hid);
            const f32x4 bev = *(const f32x4*)(be + hid);
#pragma unroll
            for (int r = 0; r < 4; r++)
                outv[mt][nt][r] = (acc[mt][nt][r] - mu) * inv * gv[r] + bev[r];
        }
    }
}

// ---------------- node encoder (K=30 padded to 32), bf16 node state ----------------
__device__ __forceinline__ float nfeat(int i, int k,
    const float* __restrict__ vel, const float* __restrict__ pos,
    const float* __restrict__ bounds, const int* __restrict__ ptype,
    const float* __restrict__ emb)
{
    if (k < 10) return vel[i * 10 + k];
    if (k < 14) {
        const int q = k - 10;
        float sub;
        if (q < 2) sub = pos[i * 2 + q] - bounds[q * 2 + 0];
        else       sub = bounds[(q - 2) * 2 + 1] - pos[i * 2 + (q - 2)];
        const float dv = sub * 20.0f;
        return fminf(fmaxf(dv, -1.0f), 1.0f);
    }
    if (k < 30) return emb[ptype[i] * 16 + (k - 14)];
    return 0.0f;
}

__global__ __launch_bounds__(256)
void k_node_enc_m(const float* __restrict__ vel, const float* __restrict__ pos,
                  const float* __restrict__ bounds, const int* __restrict__ ptype,
                  const float* __restrict__ emb,
                  const u16* __restrict__ W1p, const float* __restrict__ B1,
                  const u16* __restrict__ W2p, const float* __restrict__ B2,
                  const u16* __restrict__ W3p, const float* __restrict__ B3,
                  const float* __restrict__ g, const float* __restrict__ be,
                  u16* __restrict__ nodes_bf)
{
    __shared__ __align__(16) u16 lds[17408];
    __shared__ float red[2][2][2][16][2];
    const int tid = threadIdx.x;
    const int i0 = blockIdx.x * 64;
    for (int idx = tid; idx < 1024; idx += 256) {
        const int m = idx >> 4, kk = idx & 15;
        const int i = i0 + m;
        float f0 = 0.0f, f1 = 0.0f;
        if (i < NPART) {
            f0 = nfeat(i, kk * 2 + 0, vel, pos, bounds, ptype, emb);
            f1 = nfeat(i, kk * 2 + 1, vel, pos, bounds, ptype, emb);
        }
        *(u32*)(lds + m * 40 + kk * 2) = pack2(f0, f1);
    }
    __syncthreads();
    const int lane = tid & 63, wv = tid >> 6;
    const int wm = wv >> 1, wn = wv & 1, l15 = lane & 15, lg = lane >> 4;
    float outv[4][2][4];
    mlp_mfma<1, 40>(lds, lds, lds + 8704, red, W1p, B1, W2p, B2, W3p, B3, g, be,
                    outv, wm, wn, l15, lg, lane);
#pragma unroll
    for (int nt = 0; nt < 2; nt++) {
        const int i = i0 + wn * 32 + nt * 16 + l15;
        if (i < NPART) {
#pragma unroll
            for (int mt = 0; mt < 4; mt++) {
                const int hid = wm * 64 + mt * 16 + lg * 4;
                *(uint2*)(nodes_bf + (size_t)i * HD + hid) =
                    make_uint2(pack2(outv[mt][nt][0], outv[mt][nt][1]),
                               pack2(outv[mt][nt][2], outv[mt][nt][3]));
            }
        }
    }
}

// ------------- edge encoder (K=3 padded to 32), sorted order, bf16 output -------------
__global__ __launch_bounds__(256)
void k_edge_enc_m(const float* __restrict__ pos, const int* __restrict__ snd_s,
                  const int* __restrict__ rcv_s,
                  const u16* __restrict__ W1p, const float* __restrict__ B1,
                  const u16* __restrict__ W2p, const float* __restrict__ B2,
                  const u16* __restrict__ W3p, const float* __restrict__ B3,
                  const float* __restrict__ g, const float* __restrict__ be,
                  u16* __restrict__ edges_bf)
{
    __shared__ __align__(16) u16 lds[17408];
    __shared__ float red[2][2][2][16][2];
    const int tid = threadIdx.x;
    const int e0 = blockIdx.x * 64;
    for (int idx = tid; idx < 1024; idx += 256) {
        const int m = idx >> 4, kk = idx & 15;
        const int e = min(e0 + m, NEDGE - 1);
        u32 w = 0;
        if (kk < 2) {
            const int s = snd_s[e], r = rcv_s[e];
            const float dx = (pos[s * 2 + 0] - pos[r * 2 + 0]) * 20.0f;
            const float dy = (pos[s * 2 + 1] - pos[r * 2 + 1]) * 20.0f;
            if (kk == 0) w = pack2(dx, dy);
            else         w = pack2(sqrtf(dx * dx + dy * dy), 0.0f);
        }
        *(u32*)(lds + m * 40 + kk * 2) = w;
    }
    __syncthreads();
    const int lane = tid & 63, wv = tid >> 6;
    const int wm = wv >> 1, wn = wv & 1, l15 = lane & 15, lg = lane >> 4;
    float outv[4][2][4];
    mlp_mfma<1, 40>(lds, lds, lds + 8704, red, W1p, B1, W2p, B2, W3p, B3, g, be,
                    outv, wm, wn, l15, lg, lane);
#pragma unroll
    for (int nt = 0; nt < 2; nt++) {
        const int e = e0 + wn * 32 + nt * 16 + l15;
        if (e < NEDGE) {
#pragma unroll
            for (int mt = 0; mt < 4; mt++) {
                const int hid = wm * 64 + mt * 16 + lg * 4;
                *(uint2*)(edges_bf + (size_t)e * HD + hid) =
                    make_uint2(pack2(outv[mt][nt][0], outv[mt][nt][1]),
                               pack2(outv[mt][nt][2], outv[mt][nt][3]));
            }
        }
    }
}

// ======= 4-wave (256-thr) 32-row pipelined edge layer, bf16 state, NT streams =======
__device__ __forceinline__ void egemm_seg32(const u16* __restrict__ Wp,
                                            const u16* __restrict__ x,
                                            f32x4 acc[2][2], const int ks0,
                                            const int wm,
                                            const int l15, const int lg, const int lane)
{
    const u16* xr0 = x + l15 * 136 + lg * 8;
    const u16* xr1 = xr0 + 16 * 136;
#pragma unroll
    for (int ks = 0; ks < 4; ks++) {
        const short8 b0 = *(const short8*)(xr0 + ks * 32);
        const short8 b1 = *(const short8*)(xr1 + ks * 32);
#pragma unroll
        for (int mt = 0; mt < 2; mt++) {
            const short8 a = *(const short8*)(Wp + (((wm * 2 + mt) * 12 + ks0 + ks) * 64 + lane) * 8);
            acc[mt][0] = __builtin_amdgcn_mfma_f32_16x16x32_bf16(a, b0, acc[mt][0], 0, 0, 0);
            acc[mt][1] = __builtin_amdgcn_mfma_f32_16x16x32_bf16(a, b1, acc[mt][1], 0, 0, 0);
        }
    }
}

__device__ __forceinline__ void egemm_h32(const u16* __restrict__ Wp,
                                          const float* __restrict__ Bias,
                                          const u16* __restrict__ x,
                                          f32x4 acc[2][2],
                                          const int wm,
                                          const int l15, const int lg, const int lane)
{
#pragma unroll
    for (int mt = 0; mt < 2; mt++) {
        const f32x4 bv = *(const f32x4*)(Bias + wm * 32 + mt * 16 + lg * 4);
        acc[mt][0] = bv;
        acc[mt][1] = bv;
    }
    const u16* xr0 = x + l15 * 136 + lg * 8;
    const u16* xr1 = xr0 + 16 * 136;
#pragma unroll
    for (int ks = 0; ks < 4; ks++) {
        const short8 b0 = *(const short8*)(xr0 + ks * 32);
        const short8 b1 = *(const short8*)(xr1 + ks * 32);
#pragma unroll
        for (int mt = 0; mt < 2; mt++) {
            const short8 a = *(const short8*)(Wp + (((wm * 2 + mt) * 4 + ks) * 64 + lane) * 8);
            acc[mt][0] = __builtin_amdgcn_mfma_f32_16x16x32_bf16(a, b0, acc[mt][0], 0, 0, 0);
            acc[mt][1] = __builtin_amdgcn_mfma_f32_16x16x32_bf16(a, b1, acc[mt][1], 0, 0, 0);
        }
    }
}

// K=256 node GEMM1: 8 K-steps, xs stride 264, weight nks=8
__device__ __forceinline__ void egemm_n1(const u16* __restrict__ Wp,
                                         const float* __restrict__ Bias,
                                         const u16* __restrict__ x,
                                         f32x4 acc[2][2],
                                         const int wm,
                                         const int l15, const int lg, const int lane)
{
#pragma unroll
    for (int mt = 0; mt < 2; mt++) {
        const f32x4 bv = *(const f32x4*)(Bias + wm * 32 + mt * 16 + lg * 4);
        acc[mt][0] = bv;
        acc[mt][1] = bv;
    }
    const u16* xr0 = x + l15 * 264 + lg * 8;
    const u16* xr1 = xr0 + 16 * 264;
#pragma unroll
    for (int ks = 0; ks < 8; ks++) {
        const short8 b0 = *(const short8*)(xr0 + ks * 32);
        const short8 b1 = *(const short8*)(xr1 + ks * 32);
#pragma unroll
        for (int mt = 0; mt < 2; mt++) {
            const short8 a = *(const short8*)(Wp + (((wm * 2 + mt) * 8 + ks) * 64 + lane) * 8);
            acc[mt][0] = __builtin_amdgcn_mfma_f32_16x16x32_bf16(a, b0, acc[mt][0], 0, 0, 0);
            acc[mt][1] = __builtin_amdgcn_mfma_f32_16x16x32_bf16(a, b1, acc[mt][1], 0, 0, 0);
        }
    }
}

__device__ __forceinline__ void estore_h32(u16* __restrict__ h, const f32x4 acc[2][2],
                                           const int wm, const int l15, const int lg)
{
#pragma unroll
    for (int nt = 0; nt < 2; nt++) {
        const int row = nt * 16 + l15;
#pragma unroll
        for (int mt = 0; mt < 2; mt++) {
            const int hid = wm * 32 + mt * 16 + lg * 4;
            const f32x4 v = acc[mt][nt];
            const u32 lo = pack2(fmaxf(v[0], 0.0f), fmaxf(v[1], 0.0f));
            const u32 hi = pack2(fmaxf(v[2], 0.0f), fmaxf(v[3], 0.0f));
            *(uint2*)(h + row * 136 + hid) = make_uint2(lo, hi);
        }
    }
}

__global__ __launch_bounds__(256, 8)
void k_edge_layer_m(const u16* __restrict__ nodes_bf, u16* __restrict__ edges_bf,
                    float* __restrict__ agg, float* __restrict__ bnd,
                    const int* __restrict__ snd_s, const int* __restrict__ rcv_s,
                    const u16* __restrict__ W1p, const float* __restrict__ B1,
                    const u16* __restrict__ W2p, const float* __restrict__ B2,
                    const u16* __restrict__ W3p, const float* __restrict__ B3,
                    const float* __restrict__ g, const float* __restrict__ be)
{
    __shared__ __align__(16) u16 sb[2 * 4352];   // b0,b1: 32x136 bf16; fout overlays
    __shared__ float red[4][2][16][2];
    __shared__ int rblk[34];                     // [0..31] receivers, 32=prev, 33=next
    u16* b0 = sb;
    u16* b1 = sb + 4352;
    float* fout = (float*)sb;                    // 32 rows x stride 132 f32 = 16896B

    const int tid = threadIdx.x;
    const int tile = blockIdx.x;                 // no XCD swizzle (R9 A/B: swizzle hurt)
    const int e0 = tile * 32;                    // NEDGE/32 = 9375 blocks, exact
    const int lane = tid & 63, wm = tid >> 6;
    const int l15 = lane & 15, lg = lane >> 4;

    if (tid < 32)       rblk[tid] = rcv_s[e0 + tid];
    else if (tid == 32) rblk[32] = (e0 > 0) ? rcv_s[e0 - 1] : -2;
    else if (tid == 33) rblk[33] = (e0 + 32 < NEDGE) ? rcv_s[e0 + 32] : -2;

    // stage seg0 (edge rows, bf16, non-temporal) into b0; keep old in regs
    u32x4 e_old[2];
#pragma unroll
    for (int t = 0; t < 2; t++) {
        const int idx = tid + t * 256;
        const int m = idx >> 4, q = idx & 15;
        e_old[t] = ntl4(edges_bf + (size_t)(e0 + m) * HD + q * 8);
        *(u32x4*)(b0 + m * 136 + q * 8) = e_old[t];
    }
    // issue seg1 (sender rows, bf16, cached) loads -> regs
    u32x4 st[2];
#pragma unroll
    for (int t = 0; t < 2; t++) {
        const int idx = tid + t * 256;
        const int m = idx >> 4, q = idx & 15;
        st[t] = *(const u32x4*)(nodes_bf + (size_t)snd_s[e0 + m] * HD + q * 8);
    }
    __syncthreads();

    f32x4 acc[2][2];
#pragma unroll
    for (int mt = 0; mt < 2; mt++) {
        const f32x4 bv = *(const f32x4*)(B1 + wm * 32 + mt * 16 + lg * 4);
        acc[mt][0] = bv;
        acc[mt][1] = bv;
    }
    __builtin_amdgcn_s_setprio(1);
    egemm_seg32(W1p, b0, acc, 0, wm, l15, lg, lane);
    __builtin_amdgcn_s_setprio(0);
    // write seg1 -> b1, issue seg2 (receiver rows) loads
#pragma unroll
    for (int t = 0; t < 2; t++) {
        const int idx = tid + t * 256;
        const int m = idx >> 4, q = idx & 15;
        *(u32x4*)(b1 + m * 136 + q * 8) = st[t];
    }
#pragma unroll
    for (int t = 0; t < 2; t++) {
        const int idx = tid + t * 256;
        const int m = idx >> 4, q = idx & 15;
        st[t] = *(const u32x4*)(nodes_bf + (size_t)rcv_s[e0 + m] * HD + q * 8);
    }
    __syncthreads();

    __builtin_amdgcn_s_setprio(1);
    egemm_seg32(W1p, b1, acc, 4, wm, l15, lg, lane);
    __builtin_amdgcn_s_setprio(0);
#pragma unroll
    for (int t = 0; t < 2; t++) {
        const int idx = tid + t * 256;
        const int m = idx >> 4, q = idx & 15;
        *(u32x4*)(b0 + m * 136 + q * 8) = st[t];
    }
    __syncthreads();

    __builtin_amdgcn_s_setprio(1);
    egemm_seg32(W1p, b0, acc, 8, wm, l15, lg, lane);
    __builtin_amdgcn_s_setprio(0);
    estore_h32(b1, acc, wm, l15, lg);      // b1 free: all waves past prev barrier
    __syncthreads();

    __builtin_amdgcn_s_setprio(1);
    egemm_h32(W2p, B2, b1, acc, wm, l15, lg, lane);
    __builtin_amdgcn_s_setprio(0);
    estore_h32(b0, acc, wm, l15, lg);      // b0 free
    __syncthreads();

    __builtin_amdgcn_s_setprio(1);
    egemm_h32(W3p, B3, b0, acc, wm, l15, lg, lane);
    __builtin_amdgcn_s_setprio(0);

    // ---- layernorm reduction ----
    float ps[2], pss[2];
#pragma unroll
    for (int nt = 0; nt < 2; nt++) {
        float s = 0.0f, ss = 0.0f;
#pragma unroll
        for (int mt = 0; mt < 2; mt++) {
#pragma unroll
            for (int r = 0; r < 4; r++) {
                const float v = acc[mt][nt][r];
                s += v; ss += v * v;
            }
        }
        s += __shfl_xor(s, 16); ss += __shfl_xor(ss, 16);
        s += __shfl_xor(s, 32); ss += __shfl_xor(ss, 32);
        ps[nt] = s; pss[nt] = ss;
    }
    if (lane < 16) {
#pragma unroll
        for (int nt = 0; nt < 2; nt++) {
            red[wm][nt][l15][0] = ps[nt];
            red[wm][nt][l15][1] = pss[nt];
        }
    }
    __syncthreads();   // red ready; all waves past GEMM3 -> b0/b1 dead, fout may overlay

    // ---- LN apply -> fout (f32, stride 132) ----
#pragma unroll
    for (int nt = 0; nt < 2; nt++) {
        const float S  = red[0][nt][l15][0] + red[1][nt][l15][0]
                       + red[2][nt][l15][0] + red[3][nt][l15][0];
        const float SS = red[0][nt][l15][1] + red[1][nt][l15][1]
                       + red[2][nt][l15][1] + red[3][nt][l15][1];
        const float mu  = S * (1.0f / 128.0f);
        const float var = SS * (1.0f / 128.0f) - mu * mu;
        const float inv = rsqrtf(var + 1e-5f);
        const int row = nt * 16 + l15;
#pragma unroll
        for (int mt = 0; mt < 2; mt++) {
            const int hid = wm * 32 + mt * 16 + lg * 4;
            const f32x4 gv  = *(const f32x4*)(g + hid);
            const f32x4 bev = *(const f32x4*)(be + hid);
            f32x4 o;
#pragma unroll
            for (int r = 0; r < 4; r++)
                o[r] = (acc[mt][nt][r] - mu) * inv * gv[r] + bev[r];
            *(f32x4*)(fout + row * 132 + hid) = o;
        }
    }
    __syncthreads();

    // ---- writer: new = b2f(old regs) + ln; NT bf16 row write; new(f32) -> fout ----
#pragma unroll
    for (int t = 0; t < 2; t++) {
        const int idx = tid + t * 256;
        const int m = idx >> 4, q = idx & 15;
        float4 lo = *(const float4*)(fout + m * 132 + q * 8);
        float4 hi = *(const float4*)(fout + m * 132 + q * 8 + 4);
        const u32x4 o = e_old[t];
        lo.x += b2flo(o.x); lo.y += b2fhi(o.x);
        lo.z += b2flo(o.y); lo.w += b2fhi(o.y);
        hi.x += b2flo(o.z); hi.y += b2fhi(o.z);
        hi.z += b2flo(o.w); hi.w += b2fhi(o.w);
        *(float4*)(fout + m * 132 + q * 8) = lo;
        *(float4*)(fout + m * 132 + q * 8 + 4) = hi;
        u32x4 nv;
        nv.x = pack2(lo.x, lo.y); nv.y = pack2(lo.z, lo.w);
        nv.z = pack2(hi.x, hi.y); nv.w = pack2(hi.z, hi.w);
        nts4(nv, edges_bf + (size_t)(e0 + m) * HD + q * 8);
    }
    __syncthreads();

    // ---- aggregation: run sums -> agg (interior) or bnd (boundary), NT stores ----
    const int c = tid & 31;              // float4 chunk 0..31
    for (int ms = (tid >> 5); ms < 32; ms += 8) {
        const int rs = rblk[ms];
        if (ms > 0 && rblk[ms - 1] == rs) continue;   // not a run start
        int me = ms + 1;
        while (me < 32 && rblk[me] == rs) me++;
        f32x4 s = {0.0f, 0.0f, 0.0f, 0.0f};
        for (int m = ms; m < me; m++) {
            const float4 v = *(const float4*)(fout + m * 132 + c * 4);
            s.x += v.x; s.y += v.y; s.z += v.z; s.w += v.w;
        }
        const bool extb = (ms == 0 && rblk[32] == rs);
        const bool extf = (me == 32 && rblk[33] == rs);
        float* ap;
        if (!extb && !extf) ap = agg + (size_t)rs * HD + c * 4;
        else ap = bnd + ((size_t)tile * 2 + (extb ? 0 : 1)) * HD + c * 4;
        ntsf4(s, ap);
    }
}

// ======= 4-wave (256-thr) 32-row node layer; bf16 state, agg/bnd reassembly =======
__global__ __launch_bounds__(256)
void k_node_layer_m(u16* __restrict__ nodes_bf,
                    const float* __restrict__ agg, const float* __restrict__ bnd,
                    const int* __restrict__ row_ptr,
                    const u16* __restrict__ W1p, const float* __restrict__ B1,
                    const u16* __restrict__ W2p, const float* __restrict__ B2,
                    const u16* __restrict__ W3p, const float* __restrict__ B3,
                    const float* __restrict__ g, const float* __restrict__ be)
{
    __shared__ __align__(16) u16 xs[32 * 264];   // 16896 B; h2 overlays (stride 136)
    __shared__ __align__(16) u16 hb[32 * 136];   // 8704 B
    __shared__ float red[4][2][16][2];
    __shared__ int rp[33];
    const int tid = threadIdx.x;
    const int i0 = blockIdx.x * 32;
    const int lane = tid & 63, wm = tid >> 6;
    const int l15 = lane & 15, lg = lane >> 4;
    if (tid < 33) rp[tid] = row_ptr[min(i0 + tid, NPART)];
    __syncthreads();
    // seg A: bf16 node rows, straight copy
#pragma unroll
    for (int t = 0; t < 2; t++) {
        const int idx = tid + t * 256;
        const int m = idx >> 4, q = idx & 15;
        const int i = min(i0 + m, NPART - 1);
        *(u32x4*)(xs + m * 264 + q * 8) =
            *(const u32x4*)(nodes_bf + (size_t)i * HD + q * 8);
    }
    // seg B: agg/bnd reassembly (NT loads)
#pragma unroll
    for (int t = 0; t < 2; t++) {
        const int idx = tid + t * 256;
        const int m = idx >> 4, q = idx & 15;
        const int i = i0 + m;
        f32x4 a = {0.0f, 0.0f, 0.0f, 0.0f};
        f32x4 b = {0.0f, 0.0f, 0.0f, 0.0f};
        if (i < NPART) {
            const int p0 = rp[m], p1 = rp[m + 1];
            if (p1 > p0) {
                const int b0i = p0 >> 5, b1i = (p1 - 1) >> 5;
                if (b0i == b1i) {
                    const float* src = agg + (size_t)i * HD + q * 8;
                    a = ntlf4(src);
                    b = ntlf4(src + 4);
                } else {
                    const float* s1 = bnd + ((size_t)b0i * 2 + 1) * HD + q * 8;
                    a = ntlf4(s1);
                    b = ntlf4(s1 + 4);
                    for (int bb = b0i + 1; bb <= b1i; bb++) {
                        const float* s0 = bnd + ((size_t)bb * 2 + 0) * HD + q * 8;
                        a += ntlf4(s0);
                        b += ntlf4(s0 + 4);
                    }
                }
            }
        }
        *(u32x4*)(xs + m * 264 + 128 + q * 8) = (u32x4){
            pack2(a.x, a.y), pack2(a.z, a.w), pack2(b.x, b.y), pack2(b.z, b.w)};
    }
    __syncthreads();

    f32x4 acc[2][2];
    __builtin_amdgcn_s_setprio(1);
    egemm_n1(W1p, B1, xs, acc, wm, l15, lg, lane);
    __builtin_amdgcn_s_setprio(0);
    estore_h32(hb, acc, wm, l15, lg);       // hb disjoint from xs
    __syncthreads();
    __builtin_amdgcn_s_setprio(1);
    egemm_h32(W2p, B2, hb, acc, wm, l15, lg, lane);
    __builtin_amdgcn_s_setprio(0);
    estore_h32(xs, acc, wm, l15, lg);       // xs dead (all waves past gemm1 barrier)
    __syncthreads();
    __builtin_amdgcn_s_setprio(1);
    egemm_h32(W3p, B3, xs, acc, wm, l15, lg, lane);
    __builtin_amdgcn_s_setprio(0);

    // ---- layernorm ----
    float ps[2], pss[2];
#pragma unroll
    for (int nt = 0; nt < 2; nt++) {
        float s = 0.0f, ss = 0.0f;
#pragma unroll
        for (int mt = 0; mt < 2; mt++) {
#pragma unroll
            for (int r = 0; r < 4; r++) {
                const float v = acc[mt][nt][r];
                s += v; ss += v * v;
            }
        }
        s += __shfl_xor(s, 16); ss += __shfl_xor(ss, 16);
        s += __shfl_xor(s, 32); ss += __shfl_xor(ss, 32);
        ps[nt] = s; pss[nt] = ss;
    }
    if (lane < 16) {
#pragma unroll
        for (int nt = 0; nt < 2; nt++) {
            red[wm][nt][l15][0] = ps[nt];
            red[wm][nt][l15][1] = pss[nt];
        }
    }
    __syncthreads();

    // ---- LN apply + residual (bf16 re-read, L2-hot) + write ----
#pragma unroll
    for (int nt = 0; nt < 2; nt++) {
        const float S  = red[0][nt][l15][0] + red[1][nt][l15][0]
                       + red[2][nt][l15][0] + red[3][nt][l15][0];
        const float SS = red[0][nt][l15][1] + red[1][nt][l15][1]
                       + red[2][nt][l15][1] + red[3][nt][l15][1];
        const float mu  = S * (1.0f / 128.0f);
        const float var = SS * (1.0f / 128.0f) - mu * mu;
        const float inv = rsqrtf(var + 1e-5f);
        const int i = i0 + nt * 16 + l15;
        if (i < NPART) {
            u16* np = nodes_bf + (size_t)i * HD;
#pragma unroll
            for (int mt = 0; mt < 2; mt++) {
                const int hid = wm * 32 + mt * 16 + lg * 4;
                const f32x4 gv  = *(const f32x4*)(g + hid);
                const f32x4 bev = *(const f32x4*)(be + hid);
                const uint2 ob = *(const uint2*)(np + hid);
                float4 nv;
                nv.x = b2flo(ob.x) + (acc[mt][nt][0] - mu) * inv * gv[0] + bev[0];
                nv.y = b2fhi(ob.x) + (acc[mt][nt][1] - mu) * inv * gv[1] + bev[1];
                nv.z = b2flo(ob.y) + (acc[mt][nt][2] - mu) * inv * gv[2] + bev[2];
                nv.w = b2fhi(ob.y) + (acc[mt][nt][3] - mu) * inv * gv[3] + bev[3];
                *(uint2*)(np + hid) = make_uint2(pack2(nv.x, nv.y), pack2(nv.z, nv.w));
            }
        }
    }
}

// ---------------- fp32 gemv for decoder ----------------
template<int K, int S>
__device__ __forceinline__ void gemv(const float* __restrict__ in,
                                     const float* __restrict__ W,
                                     const float* __restrict__ B,
                                     float acc[8])
{
    const int j = threadIdx.x;
    const float bb = B[j];
#pragma unroll
    for (int m = 0; m < 8; m++) acc[m] = bb;
    constexpr int K4 = (K / 4) * 4;
    for (int k = 0; k < K4; k += 4) {
        const float w0 = W[(k + 0) * HD + j];
        const float w1 = W[(k + 1) * HD + j];
        const float w2 = W[(k + 2) * HD + j];
        const float w3 = W[(k + 3) * HD + j];
#pragma unroll
        for (int m = 0; m < 8; m++) {
            const float4 x = *(const float4*)(in + m * S + k);
            float a = acc[m];
            a = fmaf(x.x, w0, a);
            a = fmaf(x.y, w1, a);
            a = fmaf(x.z, w2, a);
            a = fmaf(x.w, w3, a);
            acc[m] = a;
        }
    }
#pragma unroll
    for (int k = K4; k < K; k++) {
        const float w = W[k * HD + j];
#pragma unroll
        for (int m = 0; m < 8; m++) acc[m] = fmaf(in[m * S + k], w, acc[m]);
    }
}

// ---------------- decoder + Euler integration (dual output dtype) ----------------
__global__ __launch_bounds__(128)
void k_decoder(const u16* __restrict__ nodes_bf,
               const float* W1, const float* B1, const float* W2, const float* B2,
               const float* W3, const float* B3,
               const float* __restrict__ vel, const float* __restrict__ pos,
               const float* __restrict__ tgt, const int* __restrict__ nonk,
               const unsigned short* __restrict__ braw, void* __restrict__ d_out)
{
    __shared__ __align__(16) float xs[8 * HD];
    __shared__ __align__(16) float h1[8 * HD];
    __shared__ __align__(16) float h2[8 * HD];
    const int j = threadIdx.x;
    const int i0 = blockIdx.x * 8;
    float acc[8];
    for (int idx = j; idx < 512; idx += 128) {
        const int m = idx >> 6, q = idx & 63;
        const u32 w = *(const u32*)(nodes_bf + (size_t)(i0 + m) * HD + q * 2);
        xs[m * HD + q * 2]     = b2flo(w);
        xs[m * HD + q * 2 + 1] = b2fhi(w);
    }
    __syncthreads();
    gemv<HD, HD>(xs, W1, B1, acc);
#pragma unroll
    for (int m = 0; m < 8; m++) h1[m * HD + j] = fmaxf(acc[m], 0.0f);
    __syncthreads();
    gemv<HD, HD>(h1, W2, B2, acc);
#pragma unroll
    for (int m = 0; m < 8; m++) h2[m * HD + j] = fmaxf(acc[m], 0.0f);
    __syncthreads();
    if (j < 16) {
        const int m = j >> 1, d = j & 1, i = i0 + m;
        float a = B3[d];
        for (int k = 0; k < HD; k++) a = fmaf(h2[m * HD + k], W3[k * 2 + d], a);
        float pp = pos[i * 2 + d] + vel[i * 10 + 8 + d] + a;
        if (nonk[i] == 0) pp = tgt[i * 2 + d];
        if (detect_bf16(braw)) {
            bf16* o = (bf16*)d_out;
            o[i * 2 + d] = __float2bfloat16(a);
            o[2 * NPART + i * 2 + d] = __float2bfloat16(pp);
        } else {
            float* o = (float*)d_out;
            o[i * 2 + d] = a;
            o[2 * NPART + i * 2 + d] = pp;
        }
    }
}

extern "C" void kernel_launch(void* const* d_in, const int* in_sizes, int n_in,
                              void* d_out, int out_size, void* d_ws, size_t ws_size,
                              hipStream_t stream)
{
    const int* ptype = (const int*)d_in[4];
    const int* nonk  = (const int*)d_in[5];
    const int* snd   = (const int*)d_in[6];
    const int* rcv   = (const int*)d_in[7];
    const unsigned short* braw = (const unsigned short*)d_in[2];

    int fmap[NFLOAT_ARRAYS];
    {
        int c = 0;
        fmap[c++] = 0; fmap[c++] = 1; fmap[c++] = 2; fmap[c++] = 3; fmap[c++] = 8;
        for (int i = 9; i <= 46; i++) fmap[c++] = i;
    }
    ConvArgs ca;
    const float* fp[47];
    float* cw = (float*)d_ws;
    int off = 0;
    for (int i = 0; i < NFLOAT_ARRAYS; i++) {
        ca.src[i] = d_in[fmap[i]];
        ca.n[i]   = in_sizes[fmap[i]];
        ca.off[i] = off;
        fp[fmap[i]] = cw + off;
        off += in_sizes[fmap[i]];
    }
    const int EB32 = NEDGE / 32;        // 9375 (edge layer, exact)
    // workspace: agg + bnd + bf16 edge state + bf16 node state + weights + sort scratch
    float* agg   = cw + ((off + 3) & ~3);
    float* bnd   = agg + (size_t)NPART * HD;
    u16* edges_bf = (u16*)(bnd + (size_t)EB32 * 2 * HD);
    u16* nodes_bf = edges_bf + (size_t)NEDGE * HD;
    u16* wpk = nodes_bf + (size_t)NPART * HD;

    // build pack table (order: ne x3, ee x3, ge x30, gn x30)
    PackArgs pa;
    int dst = 0, c = 0;
    int pk[NMAT];
    auto addm = [&](long srcoff, int K) {
        const int nk = (K + 31) / 32;
        pa.src_off[c] = (int)srcoff;
        pa.K[c] = K;
        pa.nks[c] = nk;
        pa.dst_off[c] = dst;
        pk[c] = dst;
        dst += nk * 4096;
        c++;
    };
    addm(fp[9]  - cw, 30);  addm(fp[11] - cw, 128); addm(fp[13] - cw, 128);
    addm(fp[17] - cw, 3);   addm(fp[19] - cw, 128); addm(fp[21] - cw, 128);
    for (int l = 0; l < NLAYER; l++) {
        addm(fp[25] - cw + (long)l * 384 * HD, 384);
        addm(fp[27] - cw + (long)l * HD * HD, 128);
        addm(fp[29] - cw + (long)l * HD * HD, 128);
    }
    for (int l = 0; l < NLAYER; l++) {
        addm(fp[33] - cw + (long)l * 256 * HD, 256);
        addm(fp[35] - cw + (long)l * HD * HD, 128);
        addm(fp[37] - cw + (long)l * HD * HD, 128);
    }

    int* ip = (int*)(wpk + ((dst + 7) & ~7));
    int* row_ptr = ip;            ip += NPART + 8;
    int* cursor  = ip;            ip += NPART;
    int* counts  = ip;            ip += NPART;
    int* snd_s   = ip;            ip += NEDGE;
    int* rcv_s   = ip;

    const int EBL = (NEDGE + 255) / 256;

    k_convert<<<dim3(64, NFLOAT_ARRAYS), 256, 0, stream>>>(ca, cw, braw);
    hipMemsetAsync(counts, 0, (size_t)NPART * sizeof(int), stream);
    k_hist<<<EBL, 256, 0, stream>>>(rcv, counts);
    k_scan<<<1, 1024, 0, stream>>>(counts, row_ptr, cursor);
    k_scatter<<<EBL, 256, 0, stream>>>(snd, rcv, cursor, snd_s, rcv_s);
    k_pack<<<dim3(192, NMAT), 256, 0, stream>>>(cw, wpk, pa);

    const int NB = (NPART + 63) / 64;     // 469 (encoder)
    const int NB32 = (NPART + 31) / 32;   // 938 (node layer)
    const int EB = (NEDGE + 63) / 64;     // 4688 (edge encoder)

    k_node_enc_m<<<NB, 256, 0, stream>>>(fp[0], fp[1], fp[2], ptype, fp[8],
        wpk + pk[0], fp[10], wpk + pk[1], fp[12], wpk + pk[2], fp[14],
        fp[15], fp[16], nodes_bf);
    k_edge_enc_m<<<EB, 256, 0, stream>>>(fp[1], snd_s, rcv_s,
        wpk + pk[3], fp[18], wpk + pk[4], fp[20], wpk + pk[5], fp[22],
        fp[23], fp[24], edges_bf);

    for (int l = 0; l < NLAYER; l++) {
        k_edge_layer_m<<<EB32, 256, 0, stream>>>(nodes_bf, edges_bf, agg, bnd, snd_s, rcv_s,
            wpk + pk[6 + 3 * l],  fp[26] + (size_t)l * HD,
            wpk + pk[7 + 3 * l],  fp[28] + (size_t)l * HD,
            wpk + pk[8 + 3 * l],  fp[30] + (size_t)l * HD,
            fp[31] + (size_t)l * HD, fp[32] + (size_t)l * HD);
        k_node_layer_m<<<NB32, 256, 0, stream>>>(nodes_bf, agg, bnd, row_ptr,
            wpk + pk[36 + 3 * l], fp[34] + (size_t)l * HD,
            wpk + pk[37 + 3 * l], fp[36] + (size_t)l * HD,
            wpk + pk[38 + 3 * l], fp[38] + (size_t)l * HD,
            fp[39] + (size_t)l * HD, fp[40] + (size_t)l * HD);
    }

    k_decoder<<<NPART / 8, 128, 0, stream>>>(nodes_bf,
        fp[41], fp[42], fp[43], fp[44], fp[45], fp[46],
        fp[0], fp[1], fp[3], nonk, braw, d_out);
}

// Round 12
// 1805.698 us; speedup vs baseline: 1.0542x; 1.0483x over previous
//
#include <hip/hip_runtime.h>
#include <hip/hip_bf16.h>

typedef __hip_bfloat16 bf16;
typedef unsigned short u16;
typedef unsigned int u32;
typedef __attribute__((ext_vector_type(8))) short short8;
typedef __attribute__((ext_vector_type(4))) float f32x4;
typedef __attribute__((ext_vector_type(4))) unsigned int u32x4;
typedef __attribute__((ext_vector_type(2))) unsigned int u32x2;

#define NPART 30000
#define NEDGE 300000
#define HD 128
#define NLAYER 10
#define NFLOAT_ARRAYS 43
#define NMAT 66

// ---------------- dtype detect ----------------
__device__ __forceinline__ bool detect_bf16(const unsigned short* braw) {
    return braw[1] == 0x3F80u;
}

// ---------------- fp32<->bf16 helpers (HW cvt via compiler) ----------------
__device__ __forceinline__ u16 f2b(float f) {
    const bf16 h = __float2bfloat16(f);
    u16 u;
    __builtin_memcpy(&u, &h, sizeof(u));
    return u;
}
__device__ __forceinline__ u32 pack2(float a, float b) {
    return (u32)f2b(a) | ((u32)f2b(b) << 16);
}
__device__ __forceinline__ float b2flo(u32 u) { return __uint_as_float(u << 16); }
__device__ __forceinline__ float b2fhi(u32 u) { return __uint_as_float(u & 0xFFFF0000u); }

// ---------------- non-temporal accessors (ext_vector types only) ----------------
__device__ __forceinline__ u32x4 ntl4(const u16* p) {
    return __builtin_nontemporal_load((const u32x4*)p);
}
__device__ __forceinline__ void nts4(const u32x4 v, u16* p) {
    __builtin_nontemporal_store(v, (u32x4*)p);
}
__device__ __forceinline__ void ntu2(const u32x2 v, u16* p) {
    __builtin_nontemporal_store(v, (u32x2*)p);
}

// ---------------- convert all float arrays to canonical fp32 ----------------
struct ConvArgs {
    const void* src[NFLOAT_ARRAYS];
    int n[NFLOAT_ARRAYS];
    int off[NFLOAT_ARRAYS];
};

__global__ __launch_bounds__(256)
void k_convert(ConvArgs a, float* __restrict__ dst, const unsigned short* __restrict__ braw)
{
    const bool isb = detect_bf16(braw);
    const int aid = blockIdx.y;
    const int n = a.n[aid];
    float* o = dst + a.off[aid];
    const int stride = gridDim.x * 256;
    int i = blockIdx.x * 256 + threadIdx.x;
    if (isb) {
        const unsigned short* s = (const unsigned short*)a.src[aid];
        for (; i < n; i += stride) {
            const unsigned int u = ((unsigned int)s[i]) << 16;
            o[i] = __uint_as_float(u);
        }
    } else {
        const float* s = (const float*)a.src[aid];
        for (; i < n; i += stride) o[i] = s[i];
    }
}

// ---------------- counting sort of edges by receiver ----------------
__global__ __launch_bounds__(256)
void k_hist(const int* __restrict__ rcv, int* __restrict__ counts)
{
    const int e = blockIdx.x * 256 + threadIdx.x;
    if (e < NEDGE) atomicAdd(&counts[rcv[e]], 1);
}

__global__ __launch_bounds__(1024)
void k_scan(const int* __restrict__ counts, int* __restrict__ row_ptr, int* __restrict__ cursor)
{
    __shared__ int part[1024];
    const int t = threadIdx.x;
    const int base = t * 32;
    int local[32];
    int s = 0;
#pragma unroll
    for (int k = 0; k < 32; k++) {
        const int idx = base + k;
        const int v = (idx < NPART) ? counts[idx] : 0;
        local[k] = s;
        s += v;
    }
    part[t] = s;
    __syncthreads();
    for (int off = 1; off < 1024; off <<= 1) {
        const int v = (t >= off) ? part[t - off] : 0;
        __syncthreads();
        part[t] += v;
        __syncthreads();
    }
    const int excl = (t == 0) ? 0 : part[t - 1];
#pragma unroll
    for (int k = 0; k < 32; k++) {
        const int idx = base + k;
        if (idx < NPART) {
            const int rp = excl + local[k];
            row_ptr[idx] = rp;
            cursor[idx] = rp;
        }
    }
    if (t == 0) row_ptr[NPART] = NEDGE;
}

__global__ __launch_bounds__(256)
void k_scatter(const int* __restrict__ snd, const int* __restrict__ rcv,
               int* __restrict__ cursor, int* __restrict__ snd_s, int* __restrict__ rcv_s)
{
    const int e = blockIdx.x * 256 + threadIdx.x;
    if (e < NEDGE) {
        const int r = rcv[e];
        const int p = atomicAdd(&cursor[r], 1);
        snd_s[p] = snd[e];
        rcv_s[p] = r;
    }
}

// ---------------- weight pre-pack: f32 [K][128] -> bf16 fragment-linear ----------------
struct PackArgs {
    int src_off[NMAT];
    int dst_off[NMAT];
    int K[NMAT];
    int nks[NMAT];
};

__global__ __launch_bounds__(256)
void k_pack(const float* __restrict__ cw, u16* __restrict__ wpk, PackArgs pa)
{
    const int mid = blockIdx.y;
    const int nks = pa.nks[mid];
    const int total = nks * 4096;
    const int d = blockIdx.x * 256 + threadIdx.x;
    if (d >= total) return;
    const int j = d & 7, l = (d >> 3) & 63, t = d >> 9;
    const int ks = t % nks, mt = t / nks;
    const int hid = mt * 16 + (l & 15);
    const int k = ks * 32 + (l >> 4) * 8 + j;
    const float v = (k < pa.K[mid]) ? cw[pa.src_off[mid] + k * HD + hid] : 0.0f;
    wpk[pa.dst_off[mid] + d] = f2b(v);
}

// ================= 4-wave (256-thr) 64-row MFMA MLP: encoders =================
template<int NKS, int XROW>
__device__ __forceinline__ void gemm16(const u16* __restrict__ Wp,
                                       const float* __restrict__ Bias,
                                       const u16* __restrict__ x,
                                       f32x4 acc[4][2],
                                       const int wm, const int wn,
                                       const int l15, const int lg, const int lane)
{
#pragma unroll
    for (int mt = 0; mt < 4; mt++) {
        const f32x4 bv = *(const f32x4*)(Bias + wm * 64 + mt * 16 + lg * 4);
        acc[mt][0] = bv;
        acc[mt][1] = bv;
    }
    const u16* xr0 = x + (wn * 32 + l15) * XROW + lg * 8;
    const u16* xr1 = xr0 + 16 * XROW;
    const u16* wp = Wp + (wm * 4 * NKS) * 512 + lane * 8;
#pragma unroll
    for (int ks = 0; ks < NKS; ks++) {
        const short8 b0 = *(const short8*)(xr0 + ks * 32);
        const short8 b1 = *(const short8*)(xr1 + ks * 32);
#pragma unroll
        for (int mt = 0; mt < 4; mt++) {
            const short8 a = *(const short8*)(wp + (mt * NKS + ks) * 512);
            acc[mt][0] = __builtin_amdgcn_mfma_f32_16x16x32_bf16(a, b0, acc[mt][0], 0, 0, 0);
            acc[mt][1] = __builtin_amdgcn_mfma_f32_16x16x32_bf16(a, b1, acc[mt][1], 0, 0, 0);
        }
    }
}

__device__ __forceinline__ void store_h(u16* __restrict__ h, const f32x4 acc[4][2],
                                        const int wm, const int wn, const int l15, const int lg)
{
#pragma unroll
    for (int nt = 0; nt < 2; nt++) {
        const int e = wn * 32 + nt * 16 + l15;
#pragma unroll
        for (int mt = 0; mt < 4; mt++) {
            const int hid = wm * 64 + mt * 16 + lg * 4;
            const f32x4 v = acc[mt][nt];
            const u32 lo = pack2(fmaxf(v[0], 0.0f), fmaxf(v[1], 0.0f));
            const u32 hi = pack2(fmaxf(v[2], 0.0f), fmaxf(v[3], 0.0f));
            *(uint2*)(h + e * 136 + hid) = make_uint2(lo, hi);
        }
    }
}

template<int NKS1, int XROW>
__device__ __forceinline__ void mlp_mfma(const u16* __restrict__ xs,
    u16* __restrict__ h1, u16* __restrict__ h2,
    float (*red)[2][2][16][2],
    const u16* __restrict__ W1p, const float* __restrict__ B1,
    const u16* __restrict__ W2p, const float* __restrict__ B2,
    const u16* __restrict__ W3p, const float* __restrict__ B3,
    const float* __restrict__ g, const float* __restrict__ be,
    float outv[4][2][4],
    const int wm, const int wn, const int l15, const int lg, const int lane)
{
    f32x4 acc[4][2];
    gemm16<NKS1, XROW>(W1p, B1, xs, acc, wm, wn, l15, lg, lane);
    __syncthreads();
    store_h(h1, acc, wm, wn, l15, lg);
    __syncthreads();
    gemm16<4, 136>(W2p, B2, h1, acc, wm, wn, l15, lg, lane);
    store_h(h2, acc, wm, wn, l15, lg);
    __syncthreads();
    gemm16<4, 136>(W3p, B3, h2, acc, wm, wn, l15, lg, lane);
    float ps[2], pss[2];
#pragma unroll
    for (int nt = 0; nt < 2; nt++) {
        float s = 0.0f, ss = 0.0f;
#pragma unroll
        for (int mt = 0; mt < 4; mt++) {
#pragma unroll
            for (int r = 0; r < 4; r++) {
                const float v = acc[mt][nt][r];
                s += v; ss += v * v;
            }
        }
        s += __shfl_xor(s, 16); ss += __shfl_xor(ss, 16);
        s += __shfl_xor(s, 32); ss += __shfl_xor(ss, 32);
        ps[nt] = s; pss[nt] = ss;
    }
    if (lane < 16) {
#pragma unroll
        for (int nt = 0; nt < 2; nt++) {
            red[wm][wn][nt][l15][0] = ps[nt];
            red[wm][wn][nt][l15][1] = pss[nt];
        }
    }
    __syncthreads();
#pragma unroll
    for (int nt = 0; nt < 2; nt++) {
        const float S  = red[0][wn][nt][l15][0] + red[1][wn][nt][l15][0];
        const float SS = red[0][wn][nt][l15][1] + red[1][wn][nt][l15][1];
        const float mu  = S * (1.0f / 128.0f);
        const float var = SS * (1.0f / 128.0f) - mu * mu;
        const float inv = rsqrtf(var + 1e-5f);
#pragma unroll
        for (int mt = 0; mt < 4; mt++) {
            const int hid = wm * 64 + mt * 16 + lg * 4;
            const f32x4 gv  = *(const f32x4*)(g + hid);
            const f32x4 bev = *(const f32x4*)(be + hid);
#pragma unroll
            for (int r = 0; r < 4; r++)
                outv[mt][nt][r] = (acc[mt][nt][r] - mu) * inv * gv[r] + bev[r];
        }
    }
}

// ---------------- node encoder (K=30 padded to 32), bf16 node state ----------------
__device__ __forceinline__ float nfeat(int i, int k,
    const float* __restrict__ vel, const float* __restrict__ pos,
    const float* __restrict__ bounds, const int* __restrict__ ptype,
    const float* __restrict__ emb)
{
    if (k < 10) return vel[i * 10 + k];
    if (k < 14) {
        const int q = k - 10;
        float sub;
        if (q < 2) sub = pos[i * 2 + q] - bounds[q * 2 + 0];
        else       sub = bounds[(q - 2) * 2 + 1] - pos[i * 2 + (q - 2)];
        const float dv = sub * 20.0f;
        return fminf(fmaxf(dv, -1.0f), 1.0f);
    }
    if (k < 30) return emb[ptype[i] * 16 + (k - 14)];
    return 0.0f;
}

__global__ __launch_bounds__(256)
void k_node_enc_m(const float* __restrict__ vel, const float* __restrict__ pos,
                  const float* __restrict__ bounds, const int* __restrict__ ptype,
                  const float* __restrict__ emb,
                  const u16* __restrict__ W1p, const float* __restrict__ B1,
                  const u16* __restrict__ W2p, const float* __restrict__ B2,
                  const u16* __restrict__ W3p, const float* __restrict__ B3,
                  const float* __restrict__ g, const float* __restrict__ be,
                  u16* __restrict__ nodes_bf)
{
    __shared__ __align__(16) u16 lds[17408];
    __shared__ float red[2][2][2][16][2];
    const int tid = threadIdx.x;
    const int i0 = blockIdx.x * 64;
    for (int idx = tid; idx < 1024; idx += 256) {
        const int m = idx >> 4, kk = idx & 15;
        const int i = i0 + m;
        float f0 = 0.0f, f1 = 0.0f;
        if (i < NPART) {
            f0 = nfeat(i, kk * 2 + 0, vel, pos, bounds, ptype, emb);
            f1 = nfeat(i, kk * 2 + 1, vel, pos, bounds, ptype, emb);
        }
        *(u32*)(lds + m * 40 + kk * 2) = pack2(f0, f1);
    }
    __syncthreads();
    const int lane = tid & 63, wv = tid >> 6;
    const int wm = wv >> 1, wn = wv & 1, l15 = lane & 15, lg = lane >> 4;
    float outv[4][2][4];
    mlp_mfma<1, 40>(lds, lds, lds + 8704, red, W1p, B1, W2p, B2, W3p, B3, g, be,
                    outv, wm, wn, l15, lg, lane);
#pragma unroll
    for (int nt = 0; nt < 2; nt++) {
        const int i = i0 + wn * 32 + nt * 16 + l15;
        if (i < NPART) {
#pragma unroll
            for (int mt = 0; mt < 4; mt++) {
                const int hid = wm * 64 + mt * 16 + lg * 4;
                *(uint2*)(nodes_bf + (size_t)i * HD + hid) =
                    make_uint2(pack2(outv[mt][nt][0], outv[mt][nt][1]),
                               pack2(outv[mt][nt][2], outv[mt][nt][3]));
            }
        }
    }
}

// ------------- edge encoder (K=3 padded to 32), sorted order, bf16 output -------------
__global__ __launch_bounds__(256)
void k_edge_enc_m(const float* __restrict__ pos, const int* __restrict__ snd_s,
                  const int* __restrict__ rcv_s,
                  const u16* __restrict__ W1p, const float* __restrict__ B1,
                  const u16* __restrict__ W2p, const float* __restrict__ B2,
                  const u16* __restrict__ W3p, const float* __restrict__ B3,
                  const float* __restrict__ g, const float* __restrict__ be,
                  u16* __restrict__ edges_bf)
{
    __shared__ __align__(16) u16 lds[17408];
    __shared__ float red[2][2][2][16][2];
    const int tid = threadIdx.x;
    const int e0 = blockIdx.x * 64;
    for (int idx = tid; idx < 1024; idx += 256) {
        const int m = idx >> 4, kk = idx & 15;
        const int e = min(e0 + m, NEDGE - 1);
        u32 w = 0;
        if (kk < 2) {
            const int s = snd_s[e], r = rcv_s[e];
            const float dx = (pos[s * 2 + 0] - pos[r * 2 + 0]) * 20.0f;
            const float dy = (pos[s * 2 + 1] - pos[r * 2 + 1]) * 20.0f;
            if (kk == 0) w = pack2(dx, dy);
            else         w = pack2(sqrtf(dx * dx + dy * dy), 0.0f);
        }
        *(u32*)(lds + m * 40 + kk * 2) = w;
    }
    __syncthreads();
    const int lane = tid & 63, wv = tid >> 6;
    const int wm = wv >> 1, wn = wv & 1, l15 = lane & 15, lg = lane >> 4;
    float outv[4][2][4];
    mlp_mfma<1, 40>(lds, lds, lds + 8704, red, W1p, B1, W2p, B2, W3p, B3, g, be,
                    outv, wm, wn, l15, lg, lane);
#pragma unroll
    for (int nt = 0; nt < 2; nt++) {
        const int e = e0 + wn * 32 + nt * 16 + l15;
        if (e < NEDGE) {
#pragma unroll
            for (int mt = 0; mt < 4; mt++) {
                const int hid = wm * 64 + mt * 16 + lg * 4;
                *(uint2*)(edges_bf + (size_t)e * HD + hid) =
                    make_uint2(pack2(outv[mt][nt][0], outv[mt][nt][1]),
                               pack2(outv[mt][nt][2], outv[mt][nt][3]));
            }
        }
    }
}

// ======= 4-wave (256-thr) 32-row pipelined edge layer, bf16 state, NT streams =======
__device__ __forceinline__ void egemm_seg32(const u16* __restrict__ Wp,
                                            const u16* __restrict__ x,
                                            f32x4 acc[2][2], const int ks0,
                                            const int wm,
                                            const int l15, const int lg, const int lane)
{
    const u16* xr0 = x + l15 * 136 + lg * 8;
    const u16* xr1 = xr0 + 16 * 136;
#pragma unroll
    for (int ks = 0; ks < 4; ks++) {
        const short8 b0 = *(const short8*)(xr0 + ks * 32);
        const short8 b1 = *(const short8*)(xr1 + ks * 32);
#pragma unroll
        for (int mt = 0; mt < 2; mt++) {
            const short8 a = *(const short8*)(Wp + (((wm * 2 + mt) * 12 + ks0 + ks) * 64 + lane) * 8);
            acc[mt][0] = __builtin_amdgcn_mfma_f32_16x16x32_bf16(a, b0, acc[mt][0], 0, 0, 0);
            acc[mt][1] = __builtin_amdgcn_mfma_f32_16x16x32_bf16(a, b1, acc[mt][1], 0, 0, 0);
        }
    }
}

// seg GEMM with per-lane row remap (receiver dedup: duplicate rows read run-start row)
__device__ __forceinline__ void egemm_seg32_r(const u16* __restrict__ Wp,
                                              const u16* __restrict__ x,
                                              f32x4 acc[2][2], const int ks0,
                                              const int wm, const int r0, const int r1,
                                              const int lg, const int lane)
{
    const u16* xr0 = x + r0 * 136 + lg * 8;
    const u16* xr1 = x + r1 * 136 + lg * 8;
#pragma unroll
    for (int ks = 0; ks < 4; ks++) {
        const short8 b0 = *(const short8*)(xr0 + ks * 32);
        const short8 b1 = *(const short8*)(xr1 + ks * 32);
#pragma unroll
        for (int mt = 0; mt < 2; mt++) {
            const short8 a = *(const short8*)(Wp + (((wm * 2 + mt) * 12 + ks0 + ks) * 64 + lane) * 8);
            acc[mt][0] = __builtin_amdgcn_mfma_f32_16x16x32_bf16(a, b0, acc[mt][0], 0, 0, 0);
            acc[mt][1] = __builtin_amdgcn_mfma_f32_16x16x32_bf16(a, b1, acc[mt][1], 0, 0, 0);
        }
    }
}

__device__ __forceinline__ void egemm_h32(const u16* __restrict__ Wp,
                                          const float* __restrict__ Bias,
                                          const u16* __restrict__ x,
                                          f32x4 acc[2][2],
                                          const int wm,
                                          const int l15, const int lg, const int lane)
{
#pragma unroll
    for (int mt = 0; mt < 2; mt++) {
        const f32x4 bv = *(const f32x4*)(Bias + wm * 32 + mt * 16 + lg * 4);
        acc[mt][0] = bv;
        acc[mt][1] = bv;
    }
    const u16* xr0 = x + l15 * 136 + lg * 8;
    const u16* xr1 = xr0 + 16 * 136;
#pragma unroll
    for (int ks = 0; ks < 4; ks++) {
        const short8 b0 = *(const short8*)(xr0 + ks * 32);
        const short8 b1 = *(const short8*)(xr1 + ks * 32);
#pragma unroll
        for (int mt = 0; mt < 2; mt++) {
            const short8 a = *(const short8*)(Wp + (((wm * 2 + mt) * 4 + ks) * 64 + lane) * 8);
            acc[mt][0] = __builtin_amdgcn_mfma_f32_16x16x32_bf16(a, b0, acc[mt][0], 0, 0, 0);
            acc[mt][1] = __builtin_amdgcn_mfma_f32_16x16x32_bf16(a, b1, acc[mt][1], 0, 0, 0);
        }
    }
}

// K=256 node GEMM1: 8 K-steps, xs stride 264, weight nks=8
__device__ __forceinline__ void egemm_n1(const u16* __restrict__ Wp,
                                         const float* __restrict__ Bias,
                                         const u16* __restrict__ x,
                                         f32x4 acc[2][2],
                                         const int wm,
                                         const int l15, const int lg, const int lane)
{
#pragma unroll
    for (int mt = 0; mt < 2; mt++) {
        const f32x4 bv = *(const f32x4*)(Bias + wm * 32 + mt * 16 + lg * 4);
        acc[mt][0] = bv;
        acc[mt][1] = bv;
    }
    const u16* xr0 = x + l15 * 264 + lg * 8;
    const u16* xr1 = xr0 + 16 * 264;
#pragma unroll
    for (int ks = 0; ks < 8; ks++) {
        const short8 b0 = *(const short8*)(xr0 + ks * 32);
        const short8 b1 = *(const short8*)(xr1 + ks * 32);
#pragma unroll
        for (int mt = 0; mt < 2; mt++) {
            const short8 a = *(const short8*)(Wp + (((wm * 2 + mt) * 8 + ks) * 64 + lane) * 8);
            acc[mt][0] = __builtin_amdgcn_mfma_f32_16x16x32_bf16(a, b0, acc[mt][0], 0, 0, 0);
            acc[mt][1] = __builtin_amdgcn_mfma_f32_16x16x32_bf16(a, b1, acc[mt][1], 0, 0, 0);
        }
    }
}

__device__ __forceinline__ void estore_h32(u16* __restrict__ h, const f32x4 acc[2][2],
                                           const int wm, const int l15, const int lg)
{
#pragma unroll
    for (int nt = 0; nt < 2; nt++) {
        const int row = nt * 16 + l15;
#pragma unroll
        for (int mt = 0; mt < 2; mt++) {
            const int hid = wm * 32 + mt * 16 + lg * 4;
            const f32x4 v = acc[mt][nt];
            const u32 lo = pack2(fmaxf(v[0], 0.0f), fmaxf(v[1], 0.0f));
            const u32 hi = pack2(fmaxf(v[2], 0.0f), fmaxf(v[3], 0.0f));
            *(uint2*)(h + row * 136 + hid) = make_uint2(lo, hi);
        }
    }
}

__global__ __launch_bounds__(256, 8)
void k_edge_layer_m(const u16* __restrict__ nodes_bf, u16* __restrict__ edges_bf,
                    u16* __restrict__ agg_bf, u16* __restrict__ bnd_bf,
                    const int* __restrict__ snd_s, const int* __restrict__ rcv_s,
                    const u16* __restrict__ W1p, const float* __restrict__ B1,
                    const u16* __restrict__ W2p, const float* __restrict__ B2,
                    const u16* __restrict__ W3p, const float* __restrict__ B3,
                    const float* __restrict__ g, const float* __restrict__ be)
{
    __shared__ __align__(16) u16 sb[2 * 4352];   // b0,b1: 32x136 bf16; fout overlays
    __shared__ float red[4][2][16][2];
    __shared__ int rblk[34];                     // [0..31] receivers, 32=prev, 33=next
    __shared__ int srow[32];                     // run-start row per row (dedup remap)
    u16* b0 = sb;
    u16* b1 = sb + 4352;
    float* fout = (float*)sb;                    // 32 rows x stride 132 f32 = 16896B

    const int tid = threadIdx.x;
    const int tile = blockIdx.x;
    const int e0 = tile * 32;                    // NEDGE/32 = 9375 blocks, exact
    const int lane = tid & 63, wm = tid >> 6;
    const int l15 = lane & 15, lg = lane >> 4;

    if (tid < 32)       rblk[tid] = rcv_s[e0 + tid];
    else if (tid == 32) rblk[32] = (e0 > 0) ? rcv_s[e0 - 1] : -2;
    else if (tid == 33) rblk[33] = (e0 + 32 < NEDGE) ? rcv_s[e0 + 32] : -2;

    // stage seg0 (edge rows, bf16, non-temporal) into b0; keep old in regs
    u32x4 e_old[2];
#pragma unroll
    for (int t = 0; t < 2; t++) {
        const int idx = tid + t * 256;
        const int m = idx >> 4, q = idx & 15;
        e_old[t] = ntl4(edges_bf + (size_t)(e0 + m) * HD + q * 8);
        *(u32x4*)(b0 + m * 136 + q * 8) = e_old[t];
    }
    // issue seg1 (sender rows, bf16, cached) loads -> regs
    u32x4 st[2];
#pragma unroll
    for (int t = 0; t < 2; t++) {
        const int idx = tid + t * 256;
        const int m = idx >> 4, q = idx & 15;
        st[t] = *(const u32x4*)(nodes_bf + (size_t)snd_s[e0 + m] * HD + q * 8);
    }
    __syncthreads();

    // dedup remap table (rblk complete after barrier)
    if (tid < 32) {
        const int r = rblk[tid];
        int j = tid;
        while (j > 0 && rblk[j - 1] == r) j--;
        srow[tid] = j;
    }

    f32x4 acc[2][2];
#pragma unroll
    for (int mt = 0; mt < 2; mt++) {
        const f32x4 bv = *(const f32x4*)(B1 + wm * 32 + mt * 16 + lg * 4);
        acc[mt][0] = bv;
        acc[mt][1] = bv;
    }
    __builtin_amdgcn_s_setprio(1);
    egemm_seg32(W1p, b0, acc, 0, wm, l15, lg, lane);
    __builtin_amdgcn_s_setprio(0);
    // write seg1 -> b1; issue seg2 (receiver rows, DEDUPED: run-start rows only)
#pragma unroll
    for (int t = 0; t < 2; t++) {
        const int idx = tid + t * 256;
        const int m = idx >> 4, q = idx & 15;
        *(u32x4*)(b1 + m * 136 + q * 8) = st[t];
    }
#pragma unroll
    for (int t = 0; t < 2; t++) {
        const int idx = tid + t * 256;
        const int m = idx >> 4, q = idx & 15;
        const bool is_start = (m == 0) || (rblk[m] != rblk[m - 1]);
        if (is_start)
            st[t] = *(const u32x4*)(nodes_bf + (size_t)rblk[m] * HD + q * 8);
    }
    __syncthreads();

    __builtin_amdgcn_s_setprio(1);
    egemm_seg32(W1p, b1, acc, 4, wm, l15, lg, lane);
    __builtin_amdgcn_s_setprio(0);
#pragma unroll
    for (int t = 0; t < 2; t++) {
        const int idx = tid + t * 256;
        const int m = idx >> 4, q = idx & 15;
        const bool is_start = (m == 0) || (rblk[m] != rblk[m - 1]);
        if (is_start)
            *(u32x4*)(b0 + m * 136 + q * 8) = st[t];
    }
    __syncthreads();

    // GEMM3 with row remap: duplicate rows read their run-start row
    const int sr0 = srow[l15], sr1 = srow[16 + l15];
    __builtin_amdgcn_s_setprio(1);
    egemm_seg32_r(W1p, b0, acc, 8, wm, sr0, sr1, lg, lane);
    __builtin_amdgcn_s_setprio(0);
    estore_h32(b1, acc, wm, l15, lg);      // b1 free: all waves past prev barrier
    __syncthreads();

    __builtin_amdgcn_s_setprio(1);
    egemm_h32(W2p, B2, b1, acc, wm, l15, lg, lane);
    __builtin_amdgcn_s_setprio(0);
    estore_h32(b0, acc, wm, l15, lg);      // b0 free
    __syncthreads();

    __builtin_amdgcn_s_setprio(1);
    egemm_h32(W3p, B3, b0, acc, wm, l15, lg, lane);
    __builtin_amdgcn_s_setprio(0);

    // ---- layernorm reduction ----
    float ps[2], pss[2];
#pragma unroll
    for (int nt = 0; nt < 2; nt++) {
        float s = 0.0f, ss = 0.0f;
#pragma unroll
        for (int mt = 0; mt < 2; mt++) {
#pragma unroll
            for (int r = 0; r < 4; r++) {
                const float v = acc[mt][nt][r];
                s += v; ss += v * v;
            }
        }
        s += __shfl_xor(s, 16); ss += __shfl_xor(ss, 16);
        s += __shfl_xor(s, 32); ss += __shfl_xor(ss, 32);
        ps[nt] = s; pss[nt] = ss;
    }
    if (lane < 16) {
#pragma unroll
        for (int nt = 0; nt < 2; nt++) {
            red[wm][nt][l15][0] = ps[nt];
            red[wm][nt][l15][1] = pss[nt];
        }
    }
    __syncthreads();   // red ready; all waves past GEMM3 -> b0/b1 dead, fout may overlay

    // ---- LN apply -> fout (f32, stride 132) ----
#pragma unroll
    for (int nt = 0; nt < 2; nt++) {
        const float S  = red[0][nt][l15][0] + red[1][nt][l15][0]
                       + red[2][nt][l15][0] + red[3][nt][l15][0];
        const float SS = red[0][nt][l15][1] + red[1][nt][l15][1]
                       + red[2][nt][l15][1] + red[3][nt][l15][1];
        const float mu  = S * (1.0f / 128.0f);
        const float var = SS * (1.0f / 128.0f) - mu * mu;
        const float inv = rsqrtf(var + 1e-5f);
        const int row = nt * 16 + l15;
#pragma unroll
        for (int mt = 0; mt < 2; mt++) {
            const int hid = wm * 32 + mt * 16 + lg * 4;
            const f32x4 gv  = *(const f32x4*)(g + hid);
            const f32x4 bev = *(const f32x4*)(be + hid);
            f32x4 o;
#pragma unroll
            for (int r = 0; r < 4; r++)
                o[r] = (acc[mt][nt][r] - mu) * inv * gv[r] + bev[r];
            *(f32x4*)(fout + row * 132 + hid) = o;
        }
    }
    __syncthreads();

    // ---- writer: new = b2f(old regs) + ln; NT bf16 row write; new(f32) -> fout ----
#pragma unroll
    for (int t = 0; t < 2; t++) {
        const int idx = tid + t * 256;
        const int m = idx >> 4, q = idx & 15;
        float4 lo = *(const float4*)(fout + m * 132 + q * 8);
        float4 hi = *(const float4*)(fout + m * 132 + q * 8 + 4);
        const u32x4 o = e_old[t];
        lo.x += b2flo(o.x); lo.y += b2fhi(o.x);
        lo.z += b2flo(o.y); lo.w += b2fhi(o.y);
        hi.x += b2flo(o.z); hi.y += b2fhi(o.z);
        hi.z += b2flo(o.w); hi.w += b2fhi(o.w);
        *(float4*)(fout + m * 132 + q * 8) = lo;
        *(float4*)(fout + m * 132 + q * 8 + 4) = hi;
        u32x4 nv;
        nv.x = pack2(lo.x, lo.y); nv.y = pack2(lo.z, lo.w);
        nv.z = pack2(hi.x, hi.y); nv.w = pack2(hi.z, hi.w);
        nts4(nv, edges_bf + (size_t)(e0 + m) * HD + q * 8);
    }
    __syncthreads();

    // ---- aggregation: run sums -> agg_bf (interior) or bnd_bf (boundary), NT bf16 ----
    const int c = tid & 31;              // value chunk (4 floats) 0..31
    for (int ms = (tid >> 5); ms < 32; ms += 8) {
        const int rs = rblk[ms];
        if (ms > 0 && rblk[ms - 1] == rs) continue;   // not a run start
        int me = ms + 1;
        while (me < 32 && rblk[me] == rs) me++;
        f32x4 s = {0.0f, 0.0f, 0.0f, 0.0f};
        for (int m = ms; m < me; m++) {
            const float4 v = *(const float4*)(fout + m * 132 + c * 4);
            s.x += v.x; s.y += v.y; s.z += v.z; s.w += v.w;
        }
        const u32x2 pv = {pack2(s.x, s.y), pack2(s.z, s.w)};
        const bool extb = (ms == 0 && rblk[32] == rs);
        const bool extf = (me == 32 && rblk[33] == rs);
        u16* ap;
        if (!extb && !extf) ap = agg_bf + (size_t)rs * HD + c * 4;
        else ap = bnd_bf + ((size_t)tile * 2 + (extb ? 0 : 1)) * HD + c * 4;
        ntu2(pv, ap);
    }
}

// ======= 4-wave (256-thr) 32-row node layer; bf16 state, bf16 agg/bnd reassembly =======
__global__ __launch_bounds__(256)
void k_node_layer_m(u16* __restrict__ nodes_bf,
                    const u16* __restrict__ agg_bf, const u16* __restrict__ bnd_bf,
                    const int* __restrict__ row_ptr,
                    const u16* __restrict__ W1p, const float* __restrict__ B1,
                    const u16* __restrict__ W2p, const float* __restrict__ B2,
                    const u16* __restrict__ W3p, const float* __restrict__ B3,
                    const float* __restrict__ g, const float* __restrict__ be)
{
    __shared__ __align__(16) u16 xs[32 * 264];   // 16896 B; h2 overlays (stride 136)
    __shared__ __align__(16) u16 hb[32 * 136];   // 8704 B
    __shared__ float red[4][2][16][2];
    __shared__ int rp[33];
    const int tid = threadIdx.x;
    const int i0 = blockIdx.x * 32;
    const int lane = tid & 63, wm = tid >> 6;
    const int l15 = lane & 15, lg = lane >> 4;
    if (tid < 33) rp[tid] = row_ptr[min(i0 + tid, NPART)];
    __syncthreads();
    // seg A: bf16 node rows, straight copy
#pragma unroll
    for (int t = 0; t < 2; t++) {
        const int idx = tid + t * 256;
        const int m = idx >> 4, q = idx & 15;
        const int i = min(i0 + m, NPART - 1);
        *(u32x4*)(xs + m * 264 + q * 8) =
            *(const u32x4*)(nodes_bf + (size_t)i * HD + q * 8);
    }
    // seg B: bf16 agg/bnd reassembly (interior = straight copy)
#pragma unroll
    for (int t = 0; t < 2; t++) {
        const int idx = tid + t * 256;
        const int m = idx >> 4, q = idx & 15;
        const int i = i0 + m;
        u32x4 w = {0u, 0u, 0u, 0u};
        if (i < NPART) {
            const int p0 = rp[m], p1 = rp[m + 1];
            if (p1 > p0) {
                const int b0i = p0 >> 5, b1i = (p1 - 1) >> 5;
                if (b0i == b1i) {
                    w = ntl4(agg_bf + (size_t)i * HD + q * 8);
                } else {
                    u32x4 p = ntl4(bnd_bf + ((size_t)b0i * 2 + 1) * HD + q * 8);
                    f32x4 a = {b2flo(p.x), b2fhi(p.x), b2flo(p.y), b2fhi(p.y)};
                    f32x4 b = {b2flo(p.z), b2fhi(p.z), b2flo(p.w), b2fhi(p.w)};
                    for (int bb = b0i + 1; bb <= b1i; bb++) {
                        p = ntl4(bnd_bf + ((size_t)bb * 2 + 0) * HD + q * 8);
                        a += (f32x4){b2flo(p.x), b2fhi(p.x), b2flo(p.y), b2fhi(p.y)};
                        b += (f32x4){b2flo(p.z), b2fhi(p.z), b2flo(p.w), b2fhi(p.w)};
                    }
                    w = (u32x4){pack2(a[0], a[1]), pack2(a[2], a[3]),
                                pack2(b[0], b[1]), pack2(b[2], b[3])};
                }
            }
        }
        *(u32x4*)(xs + m * 264 + 128 + q * 8) = w;
    }
    __syncthreads();

    f32x4 acc[2][2];
    __builtin_amdgcn_s_setprio(1);
    egemm_n1(W1p, B1, xs, acc, wm, l15, lg, lane);
    __builtin_amdgcn_s_setprio(0);
    estore_h32(hb, acc, wm, l15, lg);       // hb disjoint from xs
    __syncthreads();
    __builtin_amdgcn_s_setprio(1);
    egemm_h32(W2p, B2, hb, acc, wm, l15, lg, lane);
    __builtin_amdgcn_s_setprio(0);
    estore_h32(xs, acc, wm, l15, lg);       // xs dead (all waves past gemm1 barrier)
    __syncthreads();
    __builtin_amdgcn_s_setprio(1);
    egemm_h32(W3p, B3, xs, acc, wm, l15, lg, lane);
    __builtin_amdgcn_s_setprio(0);

    // ---- layernorm ----
    float ps[2], pss[2];
#pragma unroll
    for (int nt = 0; nt < 2; nt++) {
        float s = 0.0f, ss = 0.0f;
#pragma unroll
        for (int mt = 0; mt < 2; mt++) {
#pragma unroll
            for (int r = 0; r < 4; r++) {
                const float v = acc[mt][nt][r];
                s += v; ss += v * v;
            }
        }
        s += __shfl_xor(s, 16); ss += __shfl_xor(ss, 16);
        s += __shfl_xor(s, 32); ss += __shfl_xor(ss, 32);
        ps[nt] = s; pss[nt] = ss;
    }
    if (lane < 16) {
#pragma unroll
        for (int nt = 0; nt < 2; nt++) {
            red[wm][nt][l15][0] = ps[nt];
            red[wm][nt][l15][1] = pss[nt];
        }
    }
    __syncthreads();

    // ---- LN apply + residual (bf16 re-read, L2-hot) + write ----
#pragma unroll
    for (int nt = 0; nt < 2; nt++) {
        const float S  = red[0][nt][l15][0] + red[1][nt][l15][0]
                       + red[2][nt][l15][0] + red[3][nt][l15][0];
        const float SS = red[0][nt][l15][1] + red[1][nt][l15][1]
                       + red[2][nt][l15][1] + red[3][nt][l15][1];
        const float mu  = S * (1.0f / 128.0f);
        const float var = SS * (1.0f / 128.0f) - mu * mu;
        const float inv = rsqrtf(var + 1e-5f);
        const int i = i0 + nt * 16 + l15;
        if (i < NPART) {
            u16* np = nodes_bf + (size_t)i * HD;
#pragma unroll
            for (int mt = 0; mt < 2; mt++) {
                const int hid = wm * 32 + mt * 16 + lg * 4;
                const f32x4 gv  = *(const f32x4*)(g + hid);
                const f32x4 bev = *(const f32x4*)(be + hid);
                const uint2 ob = *(const uint2*)(np + hid);
                float4 nv;
                nv.x = b2flo(ob.x) + (acc[mt][nt][0] - mu) * inv * gv[0] + bev[0];
                nv.y = b2fhi(ob.x) + (acc[mt][nt][1] - mu) * inv * gv[1] + bev[1];
                nv.z = b2flo(ob.y) + (acc[mt][nt][2] - mu) * inv * gv[2] + bev[2];
                nv.w = b2fhi(ob.y) + (acc[mt][nt][3] - mu) * inv * gv[3] + bev[3];
                *(uint2*)(np + hid) = make_uint2(pack2(nv.x, nv.y), pack2(nv.z, nv.w));
            }
        }
    }
}

// ---------------- fp32 gemv for decoder ----------------
template<int K, int S>
__device__ __forceinline__ void gemv(const float* __restrict__ in,
                                     const float* __restrict__ W,
                                     const float* __restrict__ B,
                                     float acc[8])
{
    const int j = threadIdx.x;
    const float bb = B[j];
#pragma unroll
    for (int m = 0; m < 8; m++) acc[m] = bb;
    constexpr int K4 = (K / 4) * 4;
    for (int k = 0; k < K4; k += 4) {
        const float w0 = W[(k + 0) * HD + j];
        const float w1 = W[(k + 1) * HD + j];
        const float w2 = W[(k + 2) * HD + j];
        const float w3 = W[(k + 3) * HD + j];
#pragma unroll
        for (int m = 0; m < 8; m++) {
            const float4 x = *(const float4*)(in + m * S + k);
            float a = acc[m];
            a = fmaf(x.x, w0, a);
            a = fmaf(x.y, w1, a);
            a = fmaf(x.z, w2, a);
            a = fmaf(x.w, w3, a);
            acc[m] = a;
        }
    }
#pragma unroll
    for (int k = K4; k < K; k++) {
        const float w = W[k * HD + j];
#pragma unroll
        for (int m = 0; m < 8; m++) acc[m] = fmaf(in[m * S + k], w, acc[m]);
    }
}

// ---------------- decoder + Euler integration (dual output dtype) ----------------
__global__ __launch_bounds__(128)
void k_decoder(const u16* __restrict__ nodes_bf,
               const float* W1, const float* B1, const float* W2, const float* B2,
               const float* W3, const float* B3,
               const float* __restrict__ vel, const float* __restrict__ pos,
               const float* __restrict__ tgt, const int* __restrict__ nonk,
               const unsigned short* __restrict__ braw, void* __restrict__ d_out)
{
    __shared__ __align__(16) float xs[8 * HD];
    __shared__ __align__(16) float h1[8 * HD];
    __shared__ __align__(16) float h2[8 * HD];
    const int j = threadIdx.x;
    const int i0 = blockIdx.x * 8;
    float acc[8];
    for (int idx = j; idx < 512; idx += 128) {
        const int m = idx >> 6, q = idx & 63;
        const u32 w = *(const u32*)(nodes_bf + (size_t)(i0 + m) * HD + q * 2);
        xs[m * HD + q * 2]     = b2flo(w);
        xs[m * HD + q * 2 + 1] = b2fhi(w);
    }
    __syncthreads();
    gemv<HD, HD>(xs, W1, B1, acc);
#pragma unroll
    for (int m = 0; m < 8; m++) h1[m * HD + j] = fmaxf(acc[m], 0.0f);
    __syncthreads();
    gemv<HD, HD>(h1, W2, B2, acc);
#pragma unroll
    for (int m = 0; m < 8; m++) h2[m * HD + j] = fmaxf(acc[m], 0.0f);
    __syncthreads();
    if (j < 16) {
        const int m = j >> 1, d = j & 1, i = i0 + m;
        float a = B3[d];
        for (int k = 0; k < HD; k++) a = fmaf(h2[m * HD + k], W3[k * 2 + d], a);
        float pp = pos[i * 2 + d] + vel[i * 10 + 8 + d] + a;
        if (nonk[i] == 0) pp = tgt[i * 2 + d];
        if (detect_bf16(braw)) {
            bf16* o = (bf16*)d_out;
            o[i * 2 + d] = __float2bfloat16(a);
            o[2 * NPART + i * 2 + d] = __float2bfloat16(pp);
        } else {
            float* o = (float*)d_out;
            o[i * 2 + d] = a;
            o[2 * NPART + i * 2 + d] = pp;
        }
    }
}

extern "C" void kernel_launch(void* const* d_in, const int* in_sizes, int n_in,
                              void* d_out, int out_size, void* d_ws, size_t ws_size,
                              hipStream_t stream)
{
    const int* ptype = (const int*)d_in[4];
    const int* nonk  = (const int*)d_in[5];
    const int* snd   = (const int*)d_in[6];
    const int* rcv   = (const int*)d_in[7];
    const unsigned short* braw = (const unsigned short*)d_in[2];

    int fmap[NFLOAT_ARRAYS];
    {
        int c = 0;
        fmap[c++] = 0; fmap[c++] = 1; fmap[c++] = 2; fmap[c++] = 3; fmap[c++] = 8;
        for (int i = 9; i <= 46; i++) fmap[c++] = i;
    }
    ConvArgs ca;
    const float* fp[47];
    float* cw = (float*)d_ws;
    int off = 0;
    for (int i = 0; i < NFLOAT_ARRAYS; i++) {
        ca.src[i] = d_in[fmap[i]];
        ca.n[i]   = in_sizes[fmap[i]];
        ca.off[i] = off;
        fp[fmap[i]] = cw + off;
        off += in_sizes[fmap[i]];
    }
    const int EB32 = NEDGE / 32;        // 9375 (edge layer, exact)
    // workspace: bf16 edge state + bf16 node state + bf16 agg/bnd + weights + scratch
    u16* edges_bf = (u16*)(cw + ((off + 3) & ~3));
    u16* nodes_bf = edges_bf + (size_t)NEDGE * HD;
    u16* agg_bf   = nodes_bf + (size_t)NPART * HD;
    u16* bnd_bf   = agg_bf + (size_t)NPART * HD;
    u16* wpk      = bnd_bf + (size_t)EB32 * 2 * HD;

    // build pack table (order: ne x3, ee x3, ge x30, gn x30)
    PackArgs pa;
    int dst = 0, c = 0;
    int pk[NMAT];
    auto addm = [&](long srcoff, int K) {
        const int nk = (K + 31) / 32;
        pa.src_off[c] = (int)srcoff;
        pa.K[c] = K;
        pa.nks[c] = nk;
        pa.dst_off[c] = dst;
        pk[c] = dst;
        dst += nk * 4096;
        c++;
    };
    addm(fp[9]  - cw, 30);  addm(fp[11] - cw, 128); addm(fp[13] - cw, 128);
    addm(fp[17] - cw, 3);   addm(fp[19] - cw, 128); addm(fp[21] - cw, 128);
    for (int l = 0; l < NLAYER; l++) {
        addm(fp[25] - cw + (long)l * 384 * HD, 384);
        addm(fp[27] - cw + (long)l * HD * HD, 128);
        addm(fp[29] - cw + (long)l * HD * HD, 128);
    }
    for (int l = 0; l < NLAYER; l++) {
        addm(fp[33] - cw + (long)l * 256 * HD, 256);
        addm(fp[35] - cw + (long)l * HD * HD, 128);
        addm(fp[37] - cw + (long)l * HD * HD, 128);
    }

    int* ip = (int*)(wpk + ((dst + 7) & ~7));
    int* row_ptr = ip;            ip += NPART + 8;
    int* cursor  = ip;            ip += NPART;
    int* counts  = ip;            ip += NPART;
    int* snd_s   = ip;            ip += NEDGE;
    int* rcv_s   = ip;

    const int EBL = (NEDGE + 255) / 256;

    k_convert<<<dim3(64, NFLOAT_ARRAYS), 256, 0, stream>>>(ca, cw, braw);
    hipMemsetAsync(counts, 0, (size_t)NPART * sizeof(int), stream);
    k_hist<<<EBL, 256, 0, stream>>>(rcv, counts);
    k_scan<<<1, 1024, 0, stream>>>(counts, row_ptr, cursor);
    k_scatter<<<EBL, 256, 0, stream>>>(snd, rcv, cursor, snd_s, rcv_s);
    k_pack<<<dim3(192, NMAT), 256, 0, stream>>>(cw, wpk, pa);

    const int NB = (NPART + 63) / 64;     // 469 (encoder)
    const int NB32 = (NPART + 31) / 32;   // 938 (node layer)
    const int EB = (NEDGE + 63) / 64;     // 4688 (edge encoder)

    k_node_enc_m<<<NB, 256, 0, stream>>>(fp[0], fp[1], fp[2], ptype, fp[8],
        wpk + pk[0], fp[10], wpk + pk[1], fp[12], wpk + pk[2], fp[14],
        fp[15], fp[16], nodes_bf);
    k_edge_enc_m<<<EB, 256, 0, stream>>>(fp[1], snd_s, rcv_s,
        wpk + pk[3], fp[18], wpk + pk[4], fp[20], wpk + pk[5], fp[22],
        fp[23], fp[24], edges_bf);

    for (int l = 0; l < NLAYER; l++) {
        k_edge_layer_m<<<EB32, 256, 0, stream>>>(nodes_bf, edges_bf, agg_bf, bnd_bf,
            snd_s, rcv_s,
            wpk + pk[6 + 3 * l],  fp[26] + (size_t)l * HD,
            wpk + pk[7 + 3 * l],  fp[28] + (size_t)l * HD,
            wpk + pk[8 + 3 * l],  fp[30] + (size_t)l * HD,
            fp[31] + (size_t)l * HD, fp[32] + (size_t)l * HD);
        k_node_layer_m<<<NB32, 256, 0, stream>>>(nodes_bf, agg_bf, bnd_bf, row_ptr,
            wpk + pk[36 + 3 * l], fp[34] + (size_t)l * HD,
            wpk + pk[37 + 3 * l], fp[36] + (size_t)l * HD,
            wpk + pk[38 + 3 * l], fp[38] + (size_t)l * HD,
            fp[39] + (size_t)l * HD, fp[40] + (size_t)l * HD);
    }

    k_decoder<<<NPART / 8, 128, 0, stream>>>(nodes_bf,
        fp[41], fp[42], fp[43], fp[44], fp[45], fp[46],
        fp[0], fp[1], fp[3], nonk, braw, d_out);
}